// Round 9
// baseline (166.227 us; speedup 1.0000x reference)
//
#include <hip/hip_runtime.h>
#include <hip/hip_bf16.h>

// Problem constants (fixed by the reference file)
#define LEAFN 1024
#define NN    2048            // nodes per batch incl. global node 0
#define BATCH 8
#define DD    128
#define ROWS  (BATCH*NN)      // 16384
#define AHS   384             // ah row stride: [agg(128) | hL0(128) | hL1(128)]
#define NB    256             // megakernel grid (1 block/CU)
#define NT    1024            // threads per block (16 waves)

// ln(10000)/32
#define LOG1E4_OVER_32 0.28782313662425575f

// window geometry; gather: agg(32x128) = onehot(32xK) * H(Kx128), K<=224
#define SLACK 9               // proven window coverage: drift <= 9 both sides
#define CSTRIDE 136           // aggl row stride in ushorts (gemm32 A-operand)
// LDS (static 64 KB):
//   SB  (B-frag buffer, 56 tiles x 520 u16)  @ 0     .. 58240
//   msk (selector bitmask, 32 rows x 8 u32)  @ 58240 .. 59264  [persists P1->P2]
//   invdeg (f32 x32)                         @ 59264 .. 59392  [persists]
//   fb (u32)                                 @ 59392            [persists]
//   aggl (32 x CSTRIDE u16)                  @ 0 (SB reuse after MFMA barrier)
//   red / red2 (LN scratch)                  @ 61440 / 62464 (.. 63488)
// ph_tree uses 0..65024 (P0 only; msk/fb zeroed after it, pre-gbar0).
#define SB_OFF   0
#define SBT      520          // u16 per B-frag tile (512 + 8 pad: bank spread)
#define MSK_OFF  58240
#define DEG_OFF  59264
#define FB_OFF   59392
#define AGGL_OFF 0
#define RED_OFF  61440
#define RED2_OFF 62464

typedef __bf16 bf16x8 __attribute__((ext_vector_type(8)));
typedef float  floatx4 __attribute__((ext_vector_type(4)));
typedef float  floatx2 __attribute__((ext_vector_type(2)));

__device__ __forceinline__ float bf2f(unsigned short u) {
  return __uint_as_float(((unsigned)u) << 16);
}
__device__ __forceinline__ unsigned short f2bf(float f) {
  unsigned u = __float_as_uint(f);
  u += 0x7FFFu + ((u >> 16) & 1u);          // round-to-nearest-even
  return (unsigned short)(u >> 16);
}
__device__ __forceinline__ float gelu(float v) {
  return 0.5f * v * (1.0f + erff(v * 0.70710678118f));
}
__device__ __forceinline__ floatx2 bfpair(unsigned u) {
  floatx2 r;
  r[0] = __uint_as_float(u << 16);
  r[1] = __uint_as_float(u & 0xffff0000u);
  return r;
}

__device__ __forceinline__ float enc_val(int node, int d) {
  float hp, vp;
  if (node == 0) { hp = -0.5f; vp = -1.0f; }
  else {
    int v = 31 - __clz(node);
    hp = (float)(node - (1 << v));
    vp = (float)v;
  }
  float pos = (d < 64) ? hp : vp;
  int i = ((d < 64) ? d : (d - 64)) >> 1;
  float inv = __expf(-(float)i * LOG1E4_OVER_32);
  float ang = pos * inv;
  return (d & 1) ? __cosf(ang) : __sinf(ang);
}

// Cache window for block jb at level cd — MUST be identical in the eoff
// precompute and in the gather staging (single shared definition).
__device__ __forceinline__ void win_cd(int jb, int cd, int& lo_, int& wd_) {
  int g0 = 1024 + jb * 32, g1 = g0 + 31;
  int a0 = g0 >> (10 - cd), a1 = g1 >> (10 - cd);
  int l = a0 - SLACK, h = a1 + SLACK;
  int lvlo = 1 << cd, lvhi = (2 << cd) - 1;
  lo_ = l < lvlo ? lvlo : l;
  int hh = h > lvhi ? lvhi : h;
  int w = hh - lo_ + 1;
  wd_ = w < 0 ? 0 : w;
}

// ---------------------------------------------------------------------------
// Per-group barrier over 32 blocks. Group g = bid & 7.
__device__ __forceinline__ void gbarN(int* bar, int slot) {
  __syncthreads();
  if (threadIdx.x == 0) {
    int g = blockIdx.x & 7;
    int* base = bar + (slot * 8 + g) * 64;
    __threadfence();                           // release (L2 wb)
    if (__hip_atomic_fetch_add(base, 1, __ATOMIC_RELAXED,
                               __HIP_MEMORY_SCOPE_AGENT) == 31)
      __hip_atomic_store(base + 32, 1, __ATOMIC_RELAXED,
                         __HIP_MEMORY_SCOPE_AGENT);
    while (!__hip_atomic_load(base + 32, __ATOMIC_RELAXED,
                              __HIP_MEMORY_SCOPE_AGENT))
      __builtin_amdgcn_s_sleep(1);
    __threadfence();                           // acquire (L2 inv)
  }
  __syncthreads();
}

// agg store helper: 4 dims (quad j) of node g
__device__ __forceinline__ void st_agg(unsigned short* ah, int b, int g, int j,
                                       floatx4 S, float inv) {
  ushort4 o;
  o.x = f2bf(S[0] * inv); o.y = f2bf(S[1] * inv);
  o.z = f2bf(S[2] * inv); o.w = f2bf(S[3] * inv);
  *(ushort4*)&ah[(size_t)(b * NN + g) * AHS + j * 4] = o;
}

// ---------------------------------------------------------------------------
// Register-pyramid subtree sums for L1 (per-dim serial; 128 threads, thread d
// owns dim d). Whole pyramid (levels 5..0) + sroot; zero LDS, zero barriers.
__device__ __forceinline__ void aggsub_full(int b, int s, unsigned short* ah,
                                            float* __restrict__ sroot, int d) {
  float S[64];
#pragma unroll
  for (int k = 32; k < 64; ++k) {
    int c = ((16 + s) << 6) | (2 * k - 64);
    size_t a = (size_t)(b * NN + c) * AHS + 256 + d;
    float v = bf2f(ah[a]) + bf2f(ah[a + AHS]);
    S[k] = v;
    ah[(size_t)(b * NN + (((16 + s) << 5) | (k - 32))) * AHS + d] = f2bf(v * 0.5f);
  }
#pragma unroll
  for (int k = 16; k < 32; ++k) {
    int c = ((16 + s) << 5) | (2 * k - 32);
    size_t a = (size_t)(b * NN + c) * AHS + 256 + d;
    float v = bf2f(ah[a]) + bf2f(ah[a + AHS]) + S[2 * k] + S[2 * k + 1];
    S[k] = v;
    ah[(size_t)(b * NN + (((16 + s) << 4) | (k - 16))) * AHS + d] =
        f2bf(v * (1.0f / 6.0f));
  }
#pragma unroll
  for (int k = 8; k < 16; ++k) {
    int c = ((16 + s) << 4) | (2 * k - 16);
    size_t a = (size_t)(b * NN + c) * AHS + 256 + d;
    float v = bf2f(ah[a]) + bf2f(ah[a + AHS]) + S[2 * k] + S[2 * k + 1];
    S[k] = v;
    ah[(size_t)(b * NN + (((16 + s) << 3) | (k - 8))) * AHS + d] =
        f2bf(v * (1.0f / 14.0f));
  }
#pragma unroll
  for (int k = 4; k < 8; ++k) {
    int c = ((16 + s) << 3) | (2 * k - 8);
    size_t a = (size_t)(b * NN + c) * AHS + 256 + d;
    float v = bf2f(ah[a]) + bf2f(ah[a + AHS]) + S[2 * k] + S[2 * k + 1];
    S[k] = v;
    ah[(size_t)(b * NN + (((16 + s) << 2) | (k - 4))) * AHS + d] =
        f2bf(v * (1.0f / 30.0f));
  }
#pragma unroll
  for (int k = 2; k < 4; ++k) {
    int c = ((16 + s) << 2) | (2 * k - 4);
    size_t a = (size_t)(b * NN + c) * AHS + 256 + d;
    float v = bf2f(ah[a]) + bf2f(ah[a + AHS]) + S[2 * k] + S[2 * k + 1];
    S[k] = v;
    ah[(size_t)(b * NN + (((16 + s) << 1) | (k - 2))) * AHS + d] =
        f2bf(v * (1.0f / 62.0f));
  }
  {
    int c = (16 + s) << 1;
    size_t a = (size_t)(b * NN + c) * AHS + 256 + d;
    float v = bf2f(ah[a]) + bf2f(ah[a + AHS]) + S[2] + S[3];
    ah[(size_t)(b * NN + (16 + s)) * AHS + d] = f2bf(v * (1.0f / 126.0f));
    sroot[(size_t)(b * 16 + s) * DD + d] = v;
  }
}

// ---------------------------------------------------------------------------
// Tree build + layer-0 LN/GELU + in-LDS subtree sums. Pyramids run 2 levels
// per barrier-phase. Stashes x0 of the t32 tile rows into xci on WAVES 8-15.
// Writes x0 to global for leaf rows (k>=64) AND internal rows k<=32.
__device__ __forceinline__ void ph_tree(char* smemc, int b, int s,
                                        const float* __restrict__ elements,
                                        float* __restrict__ x,
                                        float* __restrict__ lvl4,
                                        unsigned short* __restrict__ ah,
                                        const float* __restrict__ gamma,
                                        const float* __restrict__ beta,
                                        float* __restrict__ sroot,
                                        float* xci, int* bar) {
  float* sm = (float*)smemc;                  // 127*128 floats = 63.5 KB
  floatx4* smv = (floatx4*)smemc;             // same memory, 32 vec4 per row
  int tid = threadIdx.x;
  const float4* src = (const float4*)(elements + (size_t)(b * LEAFN + s * 64) * DD);
  for (int i = tid; i < 2048; i += NT) {
    int f = i * 4;
    int j = f >> 7, d = f & 127;
    *(float4*)&sm[(63 + j) * DD + d] = src[i];
  }
  __syncthreads();
  // mean pyramid, fused level pairs {5,4},{3,2},{1,0} (bit-identical adds)
  {
    for (int idx = tid; idx < 16 * 32; idx += NT) {
      int k = 16 + (idx >> 5), j = idx & 31;
      floatx4 a = 0.5f * (smv[(4 * k - 1) * 32 + j] + smv[(4 * k) * 32 + j]);
      floatx4 c = 0.5f * (smv[(4 * k + 1) * 32 + j] + smv[(4 * k + 2) * 32 + j]);
      smv[(2 * k - 1) * 32 + j] = a;
      smv[(2 * k) * 32 + j] = c;
      smv[(k - 1) * 32 + j] = 0.5f * (a + c);
    }
    __syncthreads();
    for (int idx = tid; idx < 4 * 32; idx += NT) {
      int k = 4 + (idx >> 5), j = idx & 31;
      floatx4 a = 0.5f * (smv[(4 * k - 1) * 32 + j] + smv[(4 * k) * 32 + j]);
      floatx4 c = 0.5f * (smv[(4 * k + 1) * 32 + j] + smv[(4 * k + 2) * 32 + j]);
      smv[(2 * k - 1) * 32 + j] = a;
      smv[(2 * k) * 32 + j] = c;
      smv[(k - 1) * 32 + j] = 0.5f * (a + c);
    }
    __syncthreads();
    for (int idx = tid; idx < 32; idx += NT) {
      int j = idx;
      floatx4 a = 0.5f * (smv[3 * 32 + j] + smv[4 * 32 + j]);
      floatx4 c = 0.5f * (smv[5 * 32 + j] + smv[6 * 32 + j]);
      smv[1 * 32 + j] = a;
      smv[2 * 32 + j] = c;
      floatx4 r = 0.5f * (a + c);
      smv[j] = r;
      ((floatx4*)&lvl4[(size_t)(b * 16 + s) * DD])[j] = r;   // same thread, reg
    }
  }
  __syncthreads();
  if (tid == 0) {                             // release lvl4-ready flag
    __threadfence();
    __hip_atomic_store(bar + 1536 + b * 64 + s * 4, 1, __ATOMIC_RELAXED,
                       __HIP_MEMORY_SCOPE_AGENT);
  }
  // x = feat + enc; paired sin/cos (d fixed per thread: NT % 128 == 0).
  {
    int d2 = tid & 63;                        // pair index, loop-invariant
    int i = d2 & 31;
    float inv = __expf(-(float)i * LOG1E4_OVER_32);
    bool lowhalf = d2 < 32;                   // d<64 -> horizontal pos
    for (int idx2 = tid; idx2 < 127 * 64; idx2 += NT) {
      int row = idx2 >> 6;
      int k = row + 1;
      int lv = 31 - __clz(k);
      int g = ((16 + s) << lv) | (k - (1 << lv));
      float vp = (float)(lv + 4);
      float hp = (float)(g - (16 << lv));
      float pos = lowhalf ? hp : vp;
      float sv, cv;
      __sincosf(pos * inv, &sv, &cv);
      int base = row * DD + 2 * d2;
      float xv0 = sm[base] + sv;
      float xv1 = sm[base + 1] + cv;
      sm[base] = xv0; sm[base + 1] = xv1;
      if (k >= 64 || k <= 32) {
        float2 o = make_float2(xv0, xv1);
        *(float2*)&x[((size_t)(b * NN + g)) * DD + 2 * d2] = o;
      }
    }
  }
  __syncthreads();
  // stash x0 for this block's t32 gemm tile (waves 8-15 run it later)
  {
    int wave = tid >> 6, lane = tid & 63;
    if (wave >= 8) {
      int wl = wave & 7;
      int mt = wl >> 2, nq = wl & 3;
      int m = lane & 15, q = lane >> 4;
#pragma unroll
      for (int ci = 0; ci < 2; ++ci)
#pragma unroll
        for (int r = 0; r < 4; ++r) {
          int t = 32 + mt * 16 + q * 4 + r;
          int k = (t == 63) ? 1 : t + 1;
          int d = (nq * 2 + ci) * 16 + m;
          xci[ci * 4 + r] = sm[(k - 1) * DD + d];
        }
    }
  }
  __syncthreads();
  // LN + GELU: h -> ah(+128) AND h overwrites sm (fp32). float4 LDS access.
  {
    int sub = tid & 7, dp = sub * 16;
    for (int rr = tid >> 3; rr < 127; rr += NT / 8) {
      float* rowp = &sm[rr * DD + dp];
      float4 q0 = *(float4*)rowp;
      float4 q1 = *(float4*)(rowp + 4);
      float4 q2 = *(float4*)(rowp + 8);
      float4 q3 = *(float4*)(rowp + 12);
      float v[16] = {q0.x, q0.y, q0.z, q0.w, q1.x, q1.y, q1.z, q1.w,
                     q2.x, q2.y, q2.z, q2.w, q3.x, q3.y, q3.z, q3.w};
      float s1 = 0.f, s2 = 0.f;
#pragma unroll
      for (int j = 0; j < 16; ++j) { s1 += v[j]; s2 += v[j] * v[j]; }
      s1 += __shfl_xor(s1, 1); s2 += __shfl_xor(s2, 1);
      s1 += __shfl_xor(s1, 2); s2 += __shfl_xor(s2, 2);
      s1 += __shfl_xor(s1, 4); s2 += __shfl_xor(s2, 4);
      float mu = s1 * (1.0f / 128.0f);
      float var = s2 * (1.0f / 128.0f) - mu * mu;
      float rinv = rsqrtf(var + 1e-5f);
      int k = rr + 1, lv = 31 - __clz(k);
      int g = ((16 + s) << lv) | (k - (1 << lv));
      __attribute__((aligned(16))) unsigned short o[16];
      float hv[16];
#pragma unroll
      for (int j = 0; j < 16; ++j) {
        hv[j] = gelu((v[j] - mu) * rinv * gamma[dp + j] + beta[dp + j]);
        o[j] = f2bf(hv[j]);
      }
      *(float4*)rowp        = make_float4(hv[0], hv[1], hv[2], hv[3]);
      *(float4*)(rowp + 4)  = make_float4(hv[4], hv[5], hv[6], hv[7]);
      *(float4*)(rowp + 8)  = make_float4(hv[8], hv[9], hv[10], hv[11]);
      *(float4*)(rowp + 12) = make_float4(hv[12], hv[13], hv[14], hv[15]);
      unsigned short* dst = &ah[(size_t)(b * NN + g) * AHS + 128 + dp];
      *(uint4*)&dst[0] = *(uint4*)&o[0];
      *(uint4*)&dst[8] = *(uint4*)&o[8];
    }
  }
  __syncthreads();
  // subtree-sum pyramid, fused pairs {5,4},{3,2},{1,0}; agg -> ah(+0).
  // Convention: S(node n) stored at slot (2n-1). inv(lv)=1/(2^(7-lv)-2).
  {
    for (int idx = tid; idx < 16 * 32; idx += NT) {
      int k = 16 + (idx >> 5), j = idx & 31;
      floatx4 sa = smv[(4 * k - 1) * 32 + j] + smv[(4 * k) * 32 + j];
      floatx4 sc = smv[(4 * k + 1) * 32 + j] + smv[(4 * k + 2) * 32 + j];
      floatx4 sk = (smv[(2 * k - 1) * 32 + j] + smv[(2 * k) * 32 + j]) + (sa + sc);
      smv[(4 * k - 1) * 32 + j] = sa;
      smv[(4 * k + 1) * 32 + j] = sc;
      smv[(2 * k - 1) * 32 + j] = sk;
      st_agg(ah, b, ((16 + s) << 5) | (2 * k - 32), j, sa, 0.5f);
      st_agg(ah, b, ((16 + s) << 5) | (2 * k + 1 - 32), j, sc, 0.5f);
      st_agg(ah, b, ((16 + s) << 4) | (k - 16), j, sk, 1.0f / 6.0f);
    }
    __syncthreads();
    for (int idx = tid; idx < 4 * 32; idx += NT) {
      int k = 4 + (idx >> 5), j = idx & 31;
      floatx4 sa = (smv[(4 * k - 1) * 32 + j] + smv[(4 * k) * 32 + j]) +
                   (smv[(8 * k - 1) * 32 + j] + smv[(8 * k + 1) * 32 + j]);
      floatx4 sc = (smv[(4 * k + 1) * 32 + j] + smv[(4 * k + 2) * 32 + j]) +
                   (smv[(8 * k + 3) * 32 + j] + smv[(8 * k + 5) * 32 + j]);
      floatx4 sk = (smv[(2 * k - 1) * 32 + j] + smv[(2 * k) * 32 + j]) + (sa + sc);
      smv[(4 * k - 1) * 32 + j] = sa;
      smv[(4 * k + 1) * 32 + j] = sc;
      smv[(2 * k - 1) * 32 + j] = sk;
      st_agg(ah, b, ((16 + s) << 3) | (2 * k - 8), j, sa, 1.0f / 14.0f);
      st_agg(ah, b, ((16 + s) << 3) | (2 * k + 1 - 8), j, sc, 1.0f / 14.0f);
      st_agg(ah, b, ((16 + s) << 2) | (k - 4), j, sk, 1.0f / 30.0f);
    }
    __syncthreads();
    for (int idx = tid; idx < 32; idx += NT) {
      int j = idx;
      floatx4 sa = (smv[3 * 32 + j] + smv[4 * 32 + j]) +
                   (smv[7 * 32 + j] + smv[9 * 32 + j]);
      floatx4 sc = (smv[5 * 32 + j] + smv[6 * 32 + j]) +
                   (smv[11 * 32 + j] + smv[13 * 32 + j]);
      floatx4 sk = (smv[1 * 32 + j] + smv[2 * 32 + j]) + (sa + sc);
      st_agg(ah, b, ((16 + s) << 1) | 0, j, sa, 1.0f / 62.0f);
      st_agg(ah, b, ((16 + s) << 1) | 1, j, sc, 1.0f / 62.0f);
      st_agg(ah, b, (16 + s), j, sk, 1.0f / 126.0f);
      ((floatx4*)&sroot[(size_t)(b * 16 + s) * DD])[j] = sk;
    }
  }
  // caller syncs before msk-zero
}

// ---------------------------------------------------------------------------
// Top nodes 0..15: x0 into LDS xs, layer-0 h -> ah.
__device__ __forceinline__ void ph_top(char* smemc, int b,
                                       const float* __restrict__ lvl4,
                                       unsigned short* __restrict__ ah,
                                       const float* __restrict__ gamma,
                                       const float* __restrict__ beta) {
  float (*xs)[DD] = (float(*)[DD])smemc;      // 8 KB
  int tid = threadIdx.x;
  if (tid < 128) {
    int d = tid;
    float v[16];
    for (int j = 0; j < 16; ++j) v[j] = lvl4[(b * 16 + j) * DD + d];
    for (int j = 0; j < 8; ++j) v[j] = 0.5f * (v[2 * j] + v[2 * j + 1]);
    for (int j = 0; j < 8; ++j) xs[8 + j][d] = v[j] + enc_val(8 + j, d);
    for (int j = 0; j < 4; ++j) v[j] = 0.5f * (v[2 * j] + v[2 * j + 1]);
    for (int j = 0; j < 4; ++j) xs[4 + j][d] = v[j] + enc_val(4 + j, d);
    for (int j = 0; j < 2; ++j) v[j] = 0.5f * (v[2 * j] + v[2 * j + 1]);
    for (int j = 0; j < 2; ++j) xs[2 + j][d] = v[j] + enc_val(2 + j, d);
    v[0] = 0.5f * (v[0] + v[1]);
    xs[1][d] = v[0] + enc_val(1, d);
    xs[0][d] = -1.0f + enc_val(0, d);
  }
  __syncthreads();
  if (tid < 128) {
    int rr = tid >> 3, sub = tid & 7, dp = sub * 16;
    float w[16], s1 = 0.f, s2 = 0.f;
#pragma unroll
    for (int j = 0; j < 16; ++j) { w[j] = xs[rr][dp + j]; s1 += w[j]; s2 += w[j] * w[j]; }
    s1 += __shfl_xor(s1, 1); s2 += __shfl_xor(s2, 1);
    s1 += __shfl_xor(s1, 2); s2 += __shfl_xor(s2, 2);
    s1 += __shfl_xor(s1, 4); s2 += __shfl_xor(s2, 4);
    float mu = s1 * (1.0f / 128.0f);
    float var = s2 * (1.0f / 128.0f) - mu * mu;
    float rinv = rsqrtf(var + 1e-5f);
    __attribute__((aligned(16))) unsigned short o[16];
#pragma unroll
    for (int j = 0; j < 16; ++j)
      o[j] = f2bf(gelu((w[j] - mu) * rinv * gamma[dp + j] + beta[dp + j]));
    unsigned short* dst = &ah[(size_t)(b * NN + rr) * AHS + 128 + dp];
    *(uint4*)&dst[0] = *(uint4*)&o[0];
    *(uint4*)&dst[8] = *(uint4*)&o[8];
  }
  __syncthreads();
}

// ---------------------------------------------------------------------------
// MFMA leaf gather, single-pass, 2 barriers. Stage + tail-zero merged in one
// phase. MFMA on waves 0-7 (2 row strips each). When do_agg (gb<16 P2):
// waves 14-15 run the register aggsub in phase 1 and publish the per-subtree
// flag IMMEDIATELY on completion (2-wave counter), mid-leafagg — consumers
// never stall. msk/fb zeroed in P0; invdeg set here (P1).
__device__ __forceinline__ void ph_leafagg(char* smemc, int b, int jb,
                                           const int* __restrict__ srcv,
                                           const int* __restrict__ dstv,
                                           const int* __restrict__ s0a,
                                           const int* __restrict__ s1a,
                                           const unsigned short* __restrict__ eoff,
                                           unsigned short* ah, int hoff,
                                           int build, int do_agg,
                                           float* __restrict__ sroot, int* bar) {
  int tid = threadIdx.x;
  int lane = tid & 63, wv = tid >> 6;
  unsigned short* SB = (unsigned short*)(smemc + SB_OFF);
  unsigned* msk = (unsigned*)(smemc + MSK_OFF);
  float* invdeg = (float*)(smemc + DEG_OFF);
  unsigned int* fb = (unsigned int*)(smemc + FB_OFF);
  unsigned short* aggl = (unsigned short*)(smemc + AGGL_OFF);
  int rbase = b * NN + 1024 + jb * 32;

  int lo[11], wd[11], off[11];
  int acc_off = 0;
#pragma unroll
  for (int cd = 10; cd >= 1; --cd) {
    win_cd(jb, cd, lo[cd], wd[cd]);
    off[cd] = acc_off;
    acc_off += wd[cd];
  }

  int nst = do_agg ? 896 : 1024;             // stage width (waves 14-15 donate)

  // phase 1: [tid<nst] msk build (P1) + stage + tail-zero + invdeg (P1)
  //          [tid>=896 & do_agg] full register aggsub + EARLY flag publish
  if (tid < nst) {
    if (build) {
      int E0 = s0a[rbase], E1 = s1a[rbase + 31];
      for (int e = E0 + tid; e < E1; e += nst) {
        int leaf = dstv[e] - rbase;
        unsigned kr = eoff[e];
        if (kr == 0xFFFFu) atomicOr(fb, 1u << leaf);
        else atomicOr(&msk[leaf * 8 + (kr >> 5)], 1u << (kr & 31));
      }
      if (tid < 32)
        invdeg[tid] = 1.0f / (float)max(s1a[rbase + tid] - s0a[rbase + tid], 1);
    }
#pragma unroll
    for (int cd = 10; cd >= 1; --cd) {
      int w = wd[cd];
      for (int t = tid; t < w * 16; t += nst) {
        int row = t >> 4, seg = t & 15;
        int kr = off[cd] + row;
        uint4 u = *(const uint4*)&ah[(size_t)(b * NN + lo[cd] + row) * AHS + hoff + seg * 8];
        unsigned short* p = SB + ((kr >> 5) * 8 + (seg >> 1)) * SBT +
                            ((kr & 31) >> 3) * 128 + (seg & 1) * 64 + (kr & 7);
        p[0]  = (unsigned short)(u.x & 0xffff);
        p[8]  = (unsigned short)(u.x >> 16);
        p[16] = (unsigned short)(u.y & 0xffff);
        p[24] = (unsigned short)(u.y >> 16);
        p[32] = (unsigned short)(u.z & 0xffff);
        p[40] = (unsigned short)(u.z >> 16);
        p[48] = (unsigned short)(u.w & 0xffff);
        p[56] = (unsigned short)(u.w >> 16);
      }
    }
    int ntail = (224 - acc_off) * 16;
    for (int t = tid; t < ntail; t += nst) {
      int kr = acc_off + (t >> 4), seg = t & 15;
      unsigned short* p = SB + ((kr >> 5) * 8 + (seg >> 1)) * SBT +
                          ((kr & 31) >> 3) * 128 + (seg & 1) * 64 + (kr & 7);
      p[0] = 0; p[8] = 0; p[16] = 0; p[24] = 0;
      p[32] = 0; p[40] = 0; p[48] = 0; p[56] = 0;
    }
  } else if (do_agg) {
    aggsub_full(b, jb, ah, sroot, tid - 896);
    // early release: each of the 2 waves fences its drained stores, then the
    // 2nd incrementer sets the consumer-visible flag (release/acquire pair).
    if (lane == 0) {
      __threadfence();
      if (__hip_atomic_fetch_add(bar + 2048 + b * 64 + jb * 4, 1,
                                 __ATOMIC_RELAXED, __HIP_MEMORY_SCOPE_AGENT) == 1)
        __hip_atomic_store(bar + 1024 + b * 64 + jb * 4, 1, __ATOMIC_RELAXED,
                           __HIP_MEMORY_SCOPE_AGENT);
    }
  }
  __syncthreads();                                             // B2

  // phase 2: [waves 0-7] MFMA, 7 K-chunks x 2 row strips
  int m = lane & 15, q = lane >> 4;
  floatx4 acc0 = (floatx4){0.f, 0.f, 0.f, 0.f};
  floatx4 acc1 = (floatx4){0.f, 0.f, 0.f, 0.f};
  if (wv < 8) {
    int nt = wv;
#pragma unroll
    for (int kcl = 0; kcl < 7; ++kcl) {
      bf16x8 bb = *(const bf16x8*)&SB[(kcl * 8 + nt) * SBT + lane * 8];
      unsigned mw0 = msk[m * 8 + kcl];
      unsigned mw1 = msk[(16 + m) * 8 + kcl];
      unsigned b0 = (mw0 >> (q * 8)) & 0xffu;
      unsigned b1 = (mw1 >> (q * 8)) & 0xffu;
      union { uint4 u; bf16x8 v; } A0, A1;
      A0.u.x = ((b0 & 1u)  ? 0x3F80u : 0u) | ((b0 & 2u)   ? 0x3F800000u : 0u);
      A0.u.y = ((b0 & 4u)  ? 0x3F80u : 0u) | ((b0 & 8u)   ? 0x3F800000u : 0u);
      A0.u.z = ((b0 & 16u) ? 0x3F80u : 0u) | ((b0 & 32u)  ? 0x3F800000u : 0u);
      A0.u.w = ((b0 & 64u) ? 0x3F80u : 0u) | ((b0 & 128u) ? 0x3F800000u : 0u);
      A1.u.x = ((b1 & 1u)  ? 0x3F80u : 0u) | ((b1 & 2u)   ? 0x3F800000u : 0u);
      A1.u.y = ((b1 & 4u)  ? 0x3F80u : 0u) | ((b1 & 8u)   ? 0x3F800000u : 0u);
      A1.u.z = ((b1 & 16u) ? 0x3F80u : 0u) | ((b1 & 32u)  ? 0x3F800000u : 0u);
      A1.u.w = ((b1 & 64u) ? 0x3F80u : 0u) | ((b1 & 128u) ? 0x3F800000u : 0u);
      acc0 = __builtin_amdgcn_mfma_f32_16x16x32_bf16(A0.v, bb, acc0, 0, 0, 0);
      acc1 = __builtin_amdgcn_mfma_f32_16x16x32_bf16(A1.v, bb, acc1, 0, 0, 0);
    }
  }
  __syncthreads();                                             // B3 (SB dead)

  if (wv < 8) {
    unsigned fbm = *fb;
    int nt = wv;
#pragma unroll
    for (int r = 0; r < 4; ++r) {
      int l0 = q * 4 + r, l1 = 16 + q * 4 + r;
      if (!((fbm >> l0) & 1u))
        aggl[l0 * CSTRIDE + nt * 16 + m] = f2bf(acc0[r] * invdeg[l0]);
      if (!((fbm >> l1) & 1u))
        aggl[l1 * CSTRIDE + nt * 16 + m] = f2bf(acc1[r] * invdeg[l1]);
    }
    // safety net: out-of-window edges (never expected) -> scalar full redo
    if (fbm && tid < 512) {
      int leaf = tid >> 4, c = tid & 15;
      if ((fbm >> leaf) & 1u) {
        int e0 = s0a[rbase + leaf], e1 = s1a[rbase + leaf];
        floatx2 a0 = {0.f, 0.f}, a1 = {0.f, 0.f}, a2 = {0.f, 0.f}, a3 = {0.f, 0.f};
        for (int e = e0; e < e1; ++e) {
          int g = srcv[e] - b * NN;
          uint4 u = *(const uint4*)&ah[(size_t)(b * NN + g) * AHS + hoff + c * 8];
          a0 += bfpair(u.x); a1 += bfpair(u.y); a2 += bfpair(u.z); a3 += bfpair(u.w);
        }
        float inv = 1.0f / (float)max(e1 - e0, 1);
        __attribute__((aligned(16))) unsigned short o[8];
        o[0] = f2bf(a0[0] * inv); o[1] = f2bf(a0[1] * inv);
        o[2] = f2bf(a1[0] * inv); o[3] = f2bf(a1[1] * inv);
        o[4] = f2bf(a2[0] * inv); o[5] = f2bf(a2[1] * inv);
        o[6] = f2bf(a3[0] * inv); o[7] = f2bf(a3[1] * inv);
        *(uint4*)&aggl[leaf * CSTRIDE + c * 8] = *(uint4*)&o[0];
      }
    }
  }
  // caller syncs before reading aggl
}

// ---------------------------------------------------------------------------
// Finish agg for nodes 0..15 (tid<128); h at +hoff, closed-form deg.
__device__ __forceinline__ void ph_topfin(int b,
                                          const float* __restrict__ sroot,
                                          unsigned short* ah, int hoff) {
  int d = threadIdx.x;
  float S16[16], h16[16], Sv[16];
#pragma unroll
  for (int j = 0; j < 16; ++j) S16[j] = sroot[(size_t)(b * 16 + j) * DD + d];
#pragma unroll
  for (int j = 0; j < 16; ++j)
    h16[j] = bf2f(ah[(size_t)(b * NN + 16 + j) * AHS + hoff + d]);
#pragma unroll
  for (int k = 8; k < 16; ++k)
    Sv[k] = h16[2 * k - 16] + h16[2 * k - 15] + S16[2 * k - 16] + S16[2 * k - 15];
#pragma unroll
  for (int k = 7; k >= 1; --k)
    Sv[k] = bf2f(ah[(size_t)(b * NN + 2 * k) * AHS + hoff + d]) +
            bf2f(ah[(size_t)(b * NN + 2 * k + 1) * AHS + hoff + d]) +
            Sv[2 * k] + Sv[2 * k + 1];
#pragma unroll
  for (int k = 1; k < 16; ++k) {
    int dv = 31 - __clz(k);
    float inv = 1.0f / (float)((1 << (11 - dv)) - 2);
    ah[(size_t)(b * NN + k) * AHS + d] = f2bf(Sv[k] * inv);
  }
  ah[(size_t)(b * NN) * AHS + d] = f2bf(0.0f);
}

// ---------------------------------------------------------------------------
// 32-row leaf GEMM tile (contiguous rows at rowbase). agg A-operand (kc<4)
// from the aggl LDS buffer. Runs on waves 0-7 (concurrently with ph_gemm32s
// on waves 8-15); exactly 2 __syncthreads when first_layer, else 0.
__device__ __forceinline__ void ph_gemm32(char* redc, const unsigned short* aggl,
                                          int rowbase, unsigned short* ah,
                                          const unsigned short* __restrict__ wfl,
                                          const float* __restrict__ bn,
                                          float* __restrict__ x, int hoff_in,
                                          const float* __restrict__ gamma,
                                          const float* __restrict__ beta,
                                          float* xc, int first_layer) {
  int wave = threadIdx.x >> 6, lane = threadIdx.x & 63;
  bool act = wave < 8;
  int wl = wave & 7;
  int mt = wl >> 2, nq = wl & 3;
  int r0 = rowbase + mt * 16;
  int m = lane & 15, q = lane >> 4;
  floatx4 acc[2];
  acc[0] = (floatx4){0.f, 0.f, 0.f, 0.f};
  acc[1] = (floatx4){0.f, 0.f, 0.f, 0.f};
  if (act) {
    const unsigned short* arow = ah + (size_t)(r0 + m) * AHS + q * 8;
    const bf16x8* B = (const bf16x8*)wfl + lane;
#pragma unroll
    for (int kc = 0; kc < 8; ++kc) {
      bf16x8 a0;
      if (kc < 4)
        a0 = *(const bf16x8*)&aggl[(mt * 16 + m) * CSTRIDE + kc * 32 + q * 8];
      else
        a0 = *(const bf16x8*)(arow + hoff_in + (kc - 4) * 32);
#pragma unroll
      for (int ci = 0; ci < 2; ++ci) {
        bf16x8 bb = B[(kc * 8 + nq * 2 + ci) * 64];
        acc[ci] = __builtin_amdgcn_mfma_f32_16x16x32_bf16(a0, bb, acc[ci], 0, 0, 0);
      }
    }
  }
  if (first_layer) {
    float s1[4] = {0.f, 0.f, 0.f, 0.f}, s2[4] = {0.f, 0.f, 0.f, 0.f};
    if (act) {
#pragma unroll
      for (int ci = 0; ci < 2; ++ci) {
        int col = (nq * 2 + ci) * 16 + m;
        float bias = bn[col];
#pragma unroll
        for (int r = 0; r < 4; ++r) {
          int row = r0 + q * 4 + r;
          float v = x[(size_t)row * DD + col] + acc[ci][r] + bias;
          xc[ci * 4 + r] = v;
          s1[r] += v; s2[r] += v * v;
        }
      }
#pragma unroll
      for (int r = 0; r < 4; ++r) {
        s1[r] += __shfl_xor(s1[r], 1); s2[r] += __shfl_xor(s2[r], 1);
        s1[r] += __shfl_xor(s1[r], 2); s2[r] += __shfl_xor(s2[r], 2);
        s1[r] += __shfl_xor(s1[r], 4); s2[r] += __shfl_xor(s2[r], 4);
        s1[r] += __shfl_xor(s1[r], 8); s2[r] += __shfl_xor(s2[r], 8);
      }
    }
    float* red = (float*)redc;
    int rl = mt * 16 + q * 4;
    __syncthreads();
    if (act && m == 0) {
#pragma unroll
      for (int r = 0; r < 4; ++r) {
        red[(rl + r) * 4 + nq] = s1[r];
        red[128 + (rl + r) * 4 + nq] = s2[r];
      }
    }
    __syncthreads();
    if (act) {
      float mu[4], rv[4];
#pragma unroll
      for (int r = 0; r < 4; ++r) {
        float t1 = red[(rl + r) * 4] + red[(rl + r) * 4 + 1] +
                   red[(rl + r) * 4 + 2] + red[(rl + r) * 4 + 3];
        float t2 = red[128 + (rl + r) * 4] + red[128 + (rl + r) * 4 + 1] +
                   red[128 + (rl + r) * 4 + 2] + red[128 + (rl + r) * 4 + 3];
        mu[r] = t1 * (1.0f / 128.0f);
        float var = t2 * (1.0f / 128.0f) - mu[r] * mu[r];
        rv[r] = rsqrtf(var + 1e-5f);
      }
#pragma unroll
      for (int ci = 0; ci < 2; ++ci) {
        int col = (nq * 2 + ci) * 16 + m;
        float gm = gamma[col], bt = beta[col];
#pragma unroll
        for (int r = 0; r < 4; ++r) {
          int row = r0 + q * 4 + r;
          float hh = gelu((xc[ci * 4 + r] - mu[r]) * rv[r] * gm + bt);
          ah[(size_t)row * AHS + 256 + col] = f2bf(hh);
        }
      }
    }
  } else {
    if (act) {
#pragma unroll
      for (int ci = 0; ci < 2; ++ci) {
        int col = (nq * 2 + ci) * 16 + m;
        float bias = bn[col];
#pragma unroll
        for (int r = 0; r < 4; ++r) {
          int row = r0 + q * 4 + r;
          x[(size_t)row * DD + col] = xc[ci * 4 + r] + acc[ci][r] + bias;
        }
      }
    }
  }
}

// ---------------------------------------------------------------------------
// 32-row internal GEMM tile with SCATTERED rows. Runs on waves 8-15.
// first_layer residual: from gx (global x0) when gx != nullptr, else xc.
// Exactly 2 __syncthreads when first_layer, else 0 (matches ph_gemm32).
__device__ __forceinline__ void ph_gemm32s(char* redc, int b, int sb, int tbase,
                                           unsigned short* ah,
                                           const unsigned short* __restrict__ wfl,
                                           const float* __restrict__ bn,
                                           float* __restrict__ x, int hoff_in,
                                           const float* __restrict__ gamma,
                                           const float* __restrict__ beta,
                                           float* xc, int first_layer,
                                           const float* __restrict__ gx) {
  int wave = threadIdx.x >> 6, lane = threadIdx.x & 63;
  bool act = wave >= 8;
  int wl = wave & 7;
  int mt = wl >> 2, nq = wl & 3;
  int m = lane & 15, q = lane >> 4;
  int tA = tbase + mt * 16 + m;
  int kA = (tA == 63) ? 1 : tA + 1;
  int lvA = 31 - __clz(kA);
  int rowA = b * NN + (((16 + sb) << lvA) | (kA - (1 << lvA)));
  int rowO[4];
#pragma unroll
  for (int r = 0; r < 4; ++r) {
    int t = tbase + mt * 16 + q * 4 + r;
    int k = (t == 63) ? 1 : t + 1;
    int lv = 31 - __clz(k);
    rowO[r] = b * NN + (((16 + sb) << lv) | (k - (1 << lv)));
  }
  floatx4 acc[2];
  acc[0] = (floatx4){0.f, 0.f, 0.f, 0.f};
  acc[1] = (floatx4){0.f, 0.f, 0.f, 0.f};
  if (act) {
    const unsigned short* arow = ah + (size_t)rowA * AHS + q * 8;
    const bf16x8* B = (const bf16x8*)wfl + lane;
#pragma unroll
    for (int kc = 0; kc < 8; ++kc) {
      int koff = (kc < 4) ? kc * 32 : hoff_in + (kc - 4) * 32;
      bf16x8 a0 = *(const bf16x8*)(arow + koff);
#pragma unroll
      for (int ci = 0; ci < 2; ++ci) {
        bf16x8 bb = B[(kc * 8 + nq * 2 + ci) * 64];
        acc[ci] = __builtin_amdgcn_mfma_f32_16x16x32_bf16(a0, bb, acc[ci], 0, 0, 0);
      }
    }
  }
  if (first_layer) {
    float s1[4] = {0.f, 0.f, 0.f, 0.f}, s2[4] = {0.f, 0.f, 0.f, 0.f};
    if (act) {
#pragma unroll
      for (int ci = 0; ci < 2; ++ci) {
        int col = (nq * 2 + ci) * 16 + m;
        float bias = bn[col];
#pragma unroll
        for (int r = 0; r < 4; ++r) {
          float x0 = gx ? gx[(size_t)rowO[r] * DD + col] : xc[ci * 4 + r];
          float v = x0 + acc[ci][r] + bias;
          xc[ci * 4 + r] = v;
          s1[r] += v; s2[r] += v * v;
        }
      }
#pragma unroll
      for (int r = 0; r < 4; ++r) {
        s1[r] += __shfl_xor(s1[r], 1); s2[r] += __shfl_xor(s2[r], 1);
        s1[r] += __shfl_xor(s1[r], 2); s2[r] += __shfl_xor(s2[r], 2);
        s1[r] += __shfl_xor(s1[r], 4); s2[r] += __shfl_xor(s2[r], 4);
        s1[r] += __shfl_xor(s1[r], 8); s2[r] += __shfl_xor(s2[r], 8);
      }
    }
    float* red = (float*)redc;
    int rl = mt * 16 + q * 4;
    __syncthreads();
    if (act && m == 0) {
#pragma unroll
      for (int r = 0; r < 4; ++r) {
        red[(rl + r) * 4 + nq] = s1[r];
        red[128 + (rl + r) * 4 + nq] = s2[r];
      }
    }
    __syncthreads();
    if (act) {
      float mu[4], rv[4];
#pragma unroll
      for (int r = 0; r < 4; ++r) {
        float t1 = red[(rl + r) * 4] + red[(rl + r) * 4 + 1] +
                   red[(rl + r) * 4 + 2] + red[(rl + r) * 4 + 3];
        float t2 = red[128 + (rl + r) * 4] + red[128 + (rl + r) * 4 + 1] +
                   red[128 + (rl + r) * 4 + 2] + red[128 + (rl + r) * 4 + 3];
        mu[r] = t1 * (1.0f / 128.0f);
        float var = t2 * (1.0f / 128.0f) - mu[r] * mu[r];
        rv[r] = rsqrtf(var + 1e-5f);
      }
#pragma unroll
      for (int ci = 0; ci < 2; ++ci) {
        int col = (nq * 2 + ci) * 16 + m;
        float gm = gamma[col], bt = beta[col];
#pragma unroll
        for (int r = 0; r < 4; ++r) {
          float hh = gelu((xc[ci * 4 + r] - mu[r]) * rv[r] * gm + bt);
          ah[(size_t)rowO[r] * AHS + 256 + col] = f2bf(hh);
        }
      }
    }
  } else {
    if (act) {
#pragma unroll
      for (int ci = 0; ci < 2; ++ci) {
        int col = (nq * 2 + ci) * 16 + m;
        float bias = bn[col];
#pragma unroll
        for (int r = 0; r < 4; ++r)
          x[(size_t)rowO[r] * DD + col] = xc[ci * 4 + r] + acc[ci][r] + bias;
      }
    }
  }
}

// ---------------------------------------------------------------------------
// 16-row top GEMM tile (rows 0..15 of batch b). Waves 0-7 = 8 col-tiles;
// waves 8-15 inactive. Called by ALL waves (runs alone, not concurrent).
__device__ __forceinline__ void ph_gemm16t(char* redc, int b,
                                           unsigned short* ah,
                                           const unsigned short* __restrict__ wfl,
                                           const float* __restrict__ bn,
                                           float* __restrict__ x, int hoff_in,
                                           const float* __restrict__ gamma,
                                           const float* __restrict__ beta,
                                           float* xc, int first_layer) {
  int ct = threadIdx.x >> 6, lane = threadIdx.x & 63;
  bool act = ct < 8;
  int m = lane & 15, q = lane >> 4;
  floatx4 acc = (floatx4){0.f, 0.f, 0.f, 0.f};
  int col = (ct & 7) * 16 + m;
  if (act) {
    const unsigned short* arow = ah + (size_t)(b * NN + m) * AHS + q * 8;
    const bf16x8* B = (const bf16x8*)wfl + lane;
#pragma unroll
    for (int kc = 0; kc < 8; ++kc) {
      int koff = (kc < 4) ? kc * 32 : hoff_in + (kc - 4) * 32;
      bf16x8 a0 = *(const bf16x8*)(arow + koff);
      bf16x8 bb = B[(kc * 8 + ct) * 64];
      acc = __builtin_amdgcn_mfma_f32_16x16x32_bf16(a0, bb, acc, 0, 0, 0);
    }
  }
  if (first_layer) {
    float s1[4] = {0.f, 0.f, 0.f, 0.f}, s2[4] = {0.f, 0.f, 0.f, 0.f};
    float bias = act ? bn[col] : 0.f;
    if (act) {
#pragma unroll
      for (int r = 0; r < 4; ++r) {
        float v = xc[r] + acc[r] + bias;
        xc[r] = v; s1[r] = v; s2[r] = v * v;
      }
#pragma unroll
      for (int r = 0; r < 4; ++r) {
        s1[r] += __shfl_xor(s1[r], 1); s2[r] += __shfl_xor(s2[r], 1);
        s1[r] += __shfl_xor(s1[r], 2); s2[r] += __shfl_xor(s2[r], 2);
        s1[r] += __shfl_xor(s1[r], 4); s2[r] += __shfl_xor(s2[r], 4);
        s1[r] += __shfl_xor(s1[r], 8); s2[r] += __shfl_xor(s2[r], 8);
      }
    }
    float* red = (float*)redc;
    __syncthreads();
    if (act && m == 0) {
#pragma unroll
      for (int r = 0; r < 4; ++r) {
        red[(q * 4 + r) * 8 + ct] = s1[r];
        red[128 + (q * 4 + r) * 8 + ct] = s2[r];
      }
    }
    __syncthreads();
    if (act) {
#pragma unroll
      for (int r = 0; r < 4; ++r) {
        float t1 = 0.f, t2 = 0.f;
#pragma unroll
        for (int j = 0; j < 8; ++j) {
          t1 += red[(q * 4 + r) * 8 + j];
          t2 += red[128 + (q * 4 + r) * 8 + j];
        }
        float mu = t1 * (1.0f / 128.0f);
        float var = t2 * (1.0f / 128.0f) - mu * mu;
        float rv = rsqrtf(var + 1e-5f);
        float hh = gelu((xc[r] - mu) * rv * gamma[col] + beta[col]);
        ah[(size_t)(b * NN + q * 4 + r) * AHS + 256 + col] = f2bf(hh);
      }
    }
  } else {
    if (act) {
      float bias = bn[col];
#pragma unroll
      for (int r = 0; r < 4; ++r)
        x[(size_t)(b * NN + q * 4 + r) * DD + col] = xc[r] + acc[r] + bias;
    }
  }
}

// ---------------------------------------------------------------------------
// Megakernel: 8 XCD-affine groups x 32 blocks (group = bid&7 = batch).
// gb 0-15: tree + t32 tile. gb 16-31: t0 tile of subtree gb-16.
// gb 16-23: CSR + eoff precompute. gb 24-27: weight repack. gb 28: top chain.
__global__ __launch_bounds__(NT, 1) void k_mega(
    const float* __restrict__ elements, const float* __restrict__ ln_gamma,
    const float* __restrict__ ln_beta, const float* __restrict__ w_nei,
    const float* __restrict__ b_nei, const float* __restrict__ w_root,
    const int* __restrict__ srcv, const int* __restrict__ dstv, int E,
    float* __restrict__ x, int* s0a, int* s1a, float* lvl4, float* sroot,
    unsigned short* wf, unsigned short* ah, unsigned short* eoff, int* bar) {
  __shared__ __align__(16) char smem[65536];
  int bid = blockIdx.x, tid = threadIdx.x;
  int b = bid & 7, gb = bid >> 3;    // XCD-affine: batch = bid % 8
  int Eb = E >> 3;
  unsigned short* wfg = wf + (size_t)b * 65536;
  float xcl[8], xci[8], xct[4];
  int wv = tid >> 6;

  // ---- P0 ----
  if (gb < 16) {
    ph_tree(smem, b, gb, elements, x, lvl4, ah, ln_gamma, ln_beta, sroot, xci, bar);
    __syncthreads();                  // tree's last LDS writes before msk zero
  } else if (gb < 24) {
    int base = b * Eb;
    for (int i = base + (gb - 16) * NT + tid; i < base + Eb; i += 8 * NT) {
      int dv = dstv[i];
      if (i == 0 || dstv[i - 1] != dv) s0a[dv] = i;
      if (i == base + Eb - 1 || dstv[i + 1] != dv) s1a[dv] = i + 1;
    }
    // precompute per-edge concatenated window ROW index for leaf-dst edges
    for (int i = base + (gb - 16) * NT + tid; i < base + Eb; i += 8 * NT) {
      int dl = dstv[i] - b * NN - 1024;
      unsigned short ov = 0xFFFFu;
      if (dl >= 0) {
        int jb2 = dl >> 5;
        int g = srcv[i] - b * NN;
        int lv = 31 - __clz(g);
        int acc2 = 0;
#pragma unroll
        for (int cd = 10; cd >= 1; --cd) {
          int lo_, wd_;
          win_cd(jb2, cd, lo_, wd_);
          if (cd == lv) {
            int idx = g - lo_;
            if ((unsigned)idx < (unsigned)wd_)
              ov = (unsigned short)(acc2 + idx);
          }
          acc2 += wd_;
        }
      }
      eoff[i] = ov;
    }
  } else if (gb < 28) {
    int gi = (gb - 24) * NT + tid;   // 0..4095 frag units
    int lane = gi & 63, ct = (gi >> 6) & 7, kc = gi >> 9;
    int n = ct * 16 + (lane & 15);
    int k = kc * 32 + (lane >> 4) * 8;
    int kk = k & 127;
#pragma unroll
    for (int l = 0; l < 2; ++l) {
      const float* w = (k < 128) ? (w_nei + (size_t)l * DD * DD)
                                 : (w_root + (size_t)l * DD * DD);
      unsigned short* o = wfg + (size_t)l * 32768 + (size_t)gi * 8;
#pragma unroll
      for (int j = 0; j < 8; ++j) o[j] = f2bf(w[(size_t)(kk + j) * DD + n]);
    }
  } else if (gb == 28) {
    // wait for all 16 lvl4 slices of this batch, then top-node x0 + h
    if (tid < 16) {
      while (!__hip_atomic_load(bar + 1536 + b * 64 + tid * 4, __ATOMIC_RELAXED,
                                __HIP_MEMORY_SCOPE_AGENT))
        __builtin_amdgcn_s_sleep(1);
      __threadfence();
    }
    __syncthreads();
    ph_top(smem, b, lvl4, ah, ln_gamma, ln_beta);  // xs in LDS, h0..15 -> ah
    {                                              // stash xct (waves 0-7)
      int ln = tid & 63, m_ = ln & 15, q_ = ln >> 4;
      if (wv < 8) {
        float (*xs)[DD] = (float(*)[DD])smem;
#pragma unroll
        for (int r = 0; r < 4; ++r) xct[r] = xs[q_ * 4 + r][wv * 16 + m_];
      }
    }
  }
  // zero msk(256 u32) + invdeg region + fb — persists P1->P2
  if (tid < 289) *(unsigned*)(smem + MSK_OFF + 4 * tid) = 0u;
  gbarN(bar, 0);

  // ---- P1 (layer 0) ----
  if (gb == 28) {
    if (tid < 128) ph_topfin(b, sroot, ah, 128);
    __syncthreads();
    ph_gemm16t(smem + RED_OFF, b, ah, wfg, b_nei, x, 128,
               ln_gamma + DD, ln_beta + DD, xct, 1);
    __syncthreads();
  }
  ph_leafagg(smem, b, gb, srcv, dstv, s0a, s1a, eoff, ah, 128, 1, 0, sroot, bar);
  __syncthreads();
  if (wv < 8) {
    ph_gemm32(smem + RED_OFF, (const unsigned short*)(smem + AGGL_OFF),
              b * NN + 1024 + gb * 32, ah, wfg, b_nei, x, 128,
              ln_gamma + DD, ln_beta + DD, xcl, 1);
  } else if (gb < 16) {
    ph_gemm32s(smem + RED2_OFF, b, gb, 32, ah, wfg, b_nei, x, 128,
               ln_gamma + DD, ln_beta + DD, xci, 1, nullptr);
  } else {
    ph_gemm32s(smem + RED2_OFF, b, gb - 16, 0, ah, wfg, b_nei, x, 128,
               ln_gamma + DD, ln_beta + DD, xci, 1, x);
  }
  gbarN(bar, 1);

  // ---- P2 (layer 1): aggsub runs inside leafagg on waves 14-15 (gb<16) and
  // publishes its flag EARLY (mid-leafagg); consumers wait then gemm ----
  ph_leafagg(smem, b, gb, srcv, dstv, s0a, s1a, eoff, ah, 256, 0,
             (gb < 16) ? 1 : 0, sroot, bar);
  if (gb >= 16 && tid == 0) {
    // acquire subtree gb-16's aggsub output before the t0-tile gemm reads agg
    while (!__hip_atomic_load(bar + 1024 + b * 64 + (gb - 16) * 4, __ATOMIC_RELAXED,
                              __HIP_MEMORY_SCOPE_AGENT))
      __builtin_amdgcn_s_sleep(1);
    __threadfence();
  }
  __syncthreads();
  if (wv < 8) {
    ph_gemm32(smem + RED_OFF, (const unsigned short*)(smem + AGGL_OFF),
              b * NN + 1024 + gb * 32, ah, wfg + 32768, b_nei + DD,
              x, 256, ln_gamma, ln_beta, xcl, 0);
  } else if (gb < 16) {
    ph_gemm32s(smem + RED2_OFF, b, gb, 32, ah, wfg + 32768, b_nei + DD, x, 256,
               ln_gamma, ln_beta, xci, 0, nullptr);
  } else {
    ph_gemm32s(smem + RED2_OFF, b, gb - 16, 0, ah, wfg + 32768, b_nei + DD, x, 256,
               ln_gamma, ln_beta, xci, 0, nullptr);
  }
  if (gb == 28) {
    if (tid < 16) {
      while (!__hip_atomic_load(bar + 1024 + b * 64 + tid * 4, __ATOMIC_RELAXED,
                                __HIP_MEMORY_SCOPE_AGENT))
        __builtin_amdgcn_s_sleep(1);
      __threadfence();
    }
    __syncthreads();
    if (tid < 128) ph_topfin(b, sroot, ah, 256);
    __syncthreads();
    ph_gemm16t(smem + RED_OFF, b, ah, wfg + 32768, b_nei + DD, x, 256,
               ln_gamma, ln_beta, xct, 0);
  }
}

// ---------------------------------------------------------------------------
extern "C" void kernel_launch(void* const* d_in, const int* in_sizes, int n_in,
                              void* d_out, int out_size, void* d_ws, size_t ws_size,
                              hipStream_t stream) {
  const float* elements = (const float*)d_in[0];
  const float* ln_gamma = (const float*)d_in[1];
  const float* ln_beta  = (const float*)d_in[2];
  const float* w_nei    = (const float*)d_in[3];
  const float* b_nei    = (const float*)d_in[4];
  const float* w_root   = (const float*)d_in[5];
  const int*   edge     = (const int*)d_in[6];
  int E = in_sizes[6] / 2;
  const int* srcv = edge;
  const int* dstv = edge + E;
  float* x = (float*)d_out;

  char* ws = (char*)d_ws;
  int*            bar   = (int*)ws;                         // 12 KB used
  int*            s0    = (int*)(ws + 65536);               // 64 KB
  int*            s1    = (int*)(ws + 131072);              // 64 KB
  float*          lvl4  = (float*)(ws + 196608);            // 64 KB
  float*          sroot = (float*)(ws + 262144);            // 64 KB
  unsigned short* wf    = (unsigned short*)(ws + 327680);   // 1 MB (8 copies)
  unsigned short* ah    = (unsigned short*)(ws + 327680 + 1048576);  // 12.6 MB
  unsigned short* eoff  = (unsigned short*)(ws + 327680 + 1048576 + 12582912); // 2E B

  hipMemsetAsync(bar, 0, 12288, stream);
  k_mega<<<dim3(NB), dim3(NT), 0, stream>>>(
      elements, ln_gamma, ln_beta, w_nei, b_nei, w_root,
      srcv, dstv, E, x, s0, s1, lvl4, sroot, wf, ah, eoff, bar);
}

// Round 10
// 158.518 us; speedup vs baseline: 1.0486x; 1.0486x over previous
//
#include <hip/hip_runtime.h>
#include <hip/hip_bf16.h>

// Problem constants (fixed by the reference file)
#define LEAFN 1024
#define NN    2048            // nodes per batch incl. global node 0
#define BATCH 8
#define DD    128
#define ROWS  (BATCH*NN)      // 16384
#define AHS   384             // ah row stride: [agg(128) | hL0(128) | hL1(128)]
#define NB    256             // megakernel grid (1 block/CU)
#define NT    1024            // threads per block (16 waves)

// ln(10000)/32
#define LOG1E4_OVER_32 0.28782313662425575f

// window geometry; gather: agg(32x128) = onehot(32xK) * H(Kx128), K<=224
#define SLACK 9               // proven window coverage: drift <= 9 both sides
#define CSTRIDE 136           // aggl row stride in ushorts (gemm32 A-operand)
// LDS (static 64 KB):
//   SB  (B-frag buffer, 56 tiles x 520 u16)  @ 0     .. 58240
//   msk (selector bitmask, 32 rows x 8 u32)  @ 58240 .. 59264  [persists P1->P2]
//   invdeg (f32 x32)                         @ 59264 .. 59392  [persists]
//   fb (u32)                                 @ 59392            [persists]
//   aggl (32 x CSTRIDE u16)                  @ 0 (SB reuse after MFMA barrier)
//   red / red2 (LN scratch)                  @ 61440 / 62464 (.. 63488)
// ph_tree uses 0..65024 (P0 only, before msk build). aggsub uses 0..32768 (P2,
// before leafagg stage).
#define SB_OFF   0
#define SBT      520          // u16 per B-frag tile (512 + 8 pad: bank spread)
#define MSK_OFF  58240
#define DEG_OFF  59264
#define FB_OFF   59392
#define AGGL_OFF 0
#define RED_OFF  61440
#define RED2_OFF 62464

typedef __bf16 bf16x8 __attribute__((ext_vector_type(8)));
typedef float  floatx4 __attribute__((ext_vector_type(4)));
typedef float  floatx2 __attribute__((ext_vector_type(2)));

__device__ __forceinline__ float bf2f(unsigned short u) {
  return __uint_as_float(((unsigned)u) << 16);
}
__device__ __forceinline__ unsigned short f2bf(float f) {
  unsigned u = __float_as_uint(f);
  u += 0x7FFFu + ((u >> 16) & 1u);          // round-to-nearest-even
  return (unsigned short)(u >> 16);
}
__device__ __forceinline__ float gelu(float v) {
  return 0.5f * v * (1.0f + erff(v * 0.70710678118f));
}
__device__ __forceinline__ floatx2 bfpair(unsigned u) {
  floatx2 r;
  r[0] = __uint_as_float(u << 16);
  r[1] = __uint_as_float(u & 0xffff0000u);
  return r;
}

__device__ __forceinline__ float enc_val(int node, int d) {
  float hp, vp;
  if (node == 0) { hp = -0.5f; vp = -1.0f; }
  else {
    int v = 31 - __clz(node);
    hp = (float)(node - (1 << v));
    vp = (float)v;
  }
  float pos = (d < 64) ? hp : vp;
  int i = ((d < 64) ? d : (d - 64)) >> 1;
  float inv = __expf(-(float)i * LOG1E4_OVER_32);
  float ang = pos * inv;
  return (d & 1) ? __cosf(ang) : __sinf(ang);
}

// Cache window for block jb at level cd — MUST be identical in the eoff
// precompute and in the gather staging (single shared definition).
__device__ __forceinline__ void win_cd(int jb, int cd, int& lo_, int& wd_) {
  int g0 = 1024 + jb * 32, g1 = g0 + 31;
  int a0 = g0 >> (10 - cd), a1 = g1 >> (10 - cd);
  int l = a0 - SLACK, h = a1 + SLACK;
  int lvlo = 1 << cd, lvhi = (2 << cd) - 1;
  lo_ = l < lvlo ? lvlo : l;
  int hh = h > lvhi ? lvhi : h;
  int w = hh - lo_ + 1;
  wd_ = w < 0 ? 0 : w;
}

// ---------------------------------------------------------------------------
// Per-group barrier over 32 blocks. Group g = bid & 7.
__device__ __forceinline__ void gbarN(int* bar, int slot) {
  __syncthreads();
  if (threadIdx.x == 0) {
    int g = blockIdx.x & 7;
    int* base = bar + (slot * 8 + g) * 64;
    __threadfence();                           // release (L2 wb)
    if (__hip_atomic_fetch_add(base, 1, __ATOMIC_RELAXED,
                               __HIP_MEMORY_SCOPE_AGENT) == 31)
      __hip_atomic_store(base + 32, 1, __ATOMIC_RELAXED,
                         __HIP_MEMORY_SCOPE_AGENT);
    while (!__hip_atomic_load(base + 32, __ATOMIC_RELAXED,
                              __HIP_MEMORY_SCOPE_AGENT))
      __builtin_amdgcn_s_sleep(1);
    __threadfence();                           // acquire (L2 inv)
  }
  __syncthreads();
}

// agg store helper: 4 dims (quad j) of node g
__device__ __forceinline__ void st_agg(unsigned short* ah, int b, int g, int j,
                                       floatx4 S, float inv) {
  ushort4 o;
  o.x = f2bf(S[0] * inv); o.y = f2bf(S[1] * inv);
  o.z = f2bf(S[2] * inv); o.w = f2bf(S[3] * inv);
  *(ushort4*)&ah[(size_t)(b * NN + g) * AHS + j * 4] = o;
}

// ---------------------------------------------------------------------------
// Tree build + layer-0 LN/GELU + in-LDS subtree sums. Pyramids run 2 levels
// per barrier-phase (intermediate level computed in-register, both written).
// Stashes x0 of the t32 tile rows into xci on WAVES 8-15. Writes x0 to global
// for leaf rows (k>=64) AND internal rows k<=32.
__device__ __forceinline__ void ph_tree(char* smemc, int b, int s,
                                        const float* __restrict__ elements,
                                        float* __restrict__ x,
                                        float* __restrict__ lvl4,
                                        unsigned short* __restrict__ ah,
                                        const float* __restrict__ gamma,
                                        const float* __restrict__ beta,
                                        float* __restrict__ sroot,
                                        float* xci, int* bar) {
  float* sm = (float*)smemc;                  // 127*128 floats = 63.5 KB
  floatx4* smv = (floatx4*)smemc;             // same memory, 32 vec4 per row
  int tid = threadIdx.x;
  const float4* src = (const float4*)(elements + (size_t)(b * LEAFN + s * 64) * DD);
  for (int i = tid; i < 2048; i += NT) {
    int f = i * 4;
    int j = f >> 7, d = f & 127;
    *(float4*)&sm[(63 + j) * DD + d] = src[i];
  }
  __syncthreads();
  // mean pyramid, fused level pairs {5,4},{3,2},{1,0} (bit-identical adds)
  {
    for (int idx = tid; idx < 16 * 32; idx += NT) {
      int k = 16 + (idx >> 5), j = idx & 31;
      floatx4 a = 0.5f * (smv[(4 * k - 1) * 32 + j] + smv[(4 * k) * 32 + j]);
      floatx4 c = 0.5f * (smv[(4 * k + 1) * 32 + j] + smv[(4 * k + 2) * 32 + j]);
      smv[(2 * k - 1) * 32 + j] = a;
      smv[(2 * k) * 32 + j] = c;
      smv[(k - 1) * 32 + j] = 0.5f * (a + c);
    }
    __syncthreads();
    for (int idx = tid; idx < 4 * 32; idx += NT) {
      int k = 4 + (idx >> 5), j = idx & 31;
      floatx4 a = 0.5f * (smv[(4 * k - 1) * 32 + j] + smv[(4 * k) * 32 + j]);
      floatx4 c = 0.5f * (smv[(4 * k + 1) * 32 + j] + smv[(4 * k + 2) * 32 + j]);
      smv[(2 * k - 1) * 32 + j] = a;
      smv[(2 * k) * 32 + j] = c;
      smv[(k - 1) * 32 + j] = 0.5f * (a + c);
    }
    __syncthreads();
    for (int idx = tid; idx < 32; idx += NT) {
      int j = idx;
      floatx4 a = 0.5f * (smv[3 * 32 + j] + smv[4 * 32 + j]);
      floatx4 c = 0.5f * (smv[5 * 32 + j] + smv[6 * 32 + j]);
      smv[1 * 32 + j] = a;
      smv[2 * 32 + j] = c;
      floatx4 r = 0.5f * (a + c);
      smv[j] = r;
      ((floatx4*)&lvl4[(size_t)(b * 16 + s) * DD])[j] = r;   // same thread, reg
    }
  }
  __syncthreads();
  if (tid == 0) {                             // release lvl4-ready flag
    __threadfence();
    __hip_atomic_store(bar + 1536 + b * 64 + s * 4, 1, __ATOMIC_RELAXED,
                       __HIP_MEMORY_SCOPE_AGENT);
  }
  // x = feat + enc; paired sin/cos (d fixed per thread: NT % 128 == 0).
  {
    int d2 = tid & 63;                        // pair index, loop-invariant
    int i = d2 & 31;
    float inv = __expf(-(float)i * LOG1E4_OVER_32);
    bool lowhalf = d2 < 32;                   // d<64 -> horizontal pos
    for (int idx2 = tid; idx2 < 127 * 64; idx2 += NT) {
      int row = idx2 >> 6;
      int k = row + 1;
      int lv = 31 - __clz(k);
      int g = ((16 + s) << lv) | (k - (1 << lv));
      float vp = (float)(lv + 4);
      float hp = (float)(g - (16 << lv));
      float pos = lowhalf ? hp : vp;
      float sv, cv;
      __sincosf(pos * inv, &sv, &cv);
      int base = row * DD + 2 * d2;
      float xv0 = sm[base] + sv;
      float xv1 = sm[base + 1] + cv;
      sm[base] = xv0; sm[base + 1] = xv1;
      if (k >= 64 || k <= 32) {
        float2 o = make_float2(xv0, xv1);
        *(float2*)&x[((size_t)(b * NN + g)) * DD + 2 * d2] = o;
      }
    }
  }
  __syncthreads();
  // stash x0 for this block's t32 gemm tile (waves 8-15 run it later)
  {
    int wave = tid >> 6, lane = tid & 63;
    if (wave >= 8) {
      int wl = wave & 7;
      int mt = wl >> 2, nq = wl & 3;
      int m = lane & 15, q = lane >> 4;
#pragma unroll
      for (int ci = 0; ci < 2; ++ci)
#pragma unroll
        for (int r = 0; r < 4; ++r) {
          int t = 32 + mt * 16 + q * 4 + r;
          int k = (t == 63) ? 1 : t + 1;
          int d = (nq * 2 + ci) * 16 + m;
          xci[ci * 4 + r] = sm[(k - 1) * DD + d];
        }
    }
  }
  __syncthreads();
  // LN + GELU: h -> ah(+128) AND h overwrites sm (fp32). float4 LDS access.
  {
    int sub = tid & 7, dp = sub * 16;
    for (int rr = tid >> 3; rr < 127; rr += NT / 8) {
      float* rowp = &sm[rr * DD + dp];
      float4 q0 = *(float4*)rowp;
      float4 q1 = *(float4*)(rowp + 4);
      float4 q2 = *(float4*)(rowp + 8);
      float4 q3 = *(float4*)(rowp + 12);
      float v[16] = {q0.x, q0.y, q0.z, q0.w, q1.x, q1.y, q1.z, q1.w,
                     q2.x, q2.y, q2.z, q2.w, q3.x, q3.y, q3.z, q3.w};
      float s1 = 0.f, s2 = 0.f;
#pragma unroll
      for (int j = 0; j < 16; ++j) { s1 += v[j]; s2 += v[j] * v[j]; }
      s1 += __shfl_xor(s1, 1); s2 += __shfl_xor(s2, 1);
      s1 += __shfl_xor(s1, 2); s2 += __shfl_xor(s2, 2);
      s1 += __shfl_xor(s1, 4); s2 += __shfl_xor(s2, 4);
      float mu = s1 * (1.0f / 128.0f);
      float var = s2 * (1.0f / 128.0f) - mu * mu;
      float rinv = rsqrtf(var + 1e-5f);
      int k = rr + 1, lv = 31 - __clz(k);
      int g = ((16 + s) << lv) | (k - (1 << lv));
      __attribute__((aligned(16))) unsigned short o[16];
      float hv[16];
#pragma unroll
      for (int j = 0; j < 16; ++j) {
        hv[j] = gelu((v[j] - mu) * rinv * gamma[dp + j] + beta[dp + j]);
        o[j] = f2bf(hv[j]);
      }
      *(float4*)rowp        = make_float4(hv[0], hv[1], hv[2], hv[3]);
      *(float4*)(rowp + 4)  = make_float4(hv[4], hv[5], hv[6], hv[7]);
      *(float4*)(rowp + 8)  = make_float4(hv[8], hv[9], hv[10], hv[11]);
      *(float4*)(rowp + 12) = make_float4(hv[12], hv[13], hv[14], hv[15]);
      unsigned short* dst = &ah[(size_t)(b * NN + g) * AHS + 128 + dp];
      *(uint4*)&dst[0] = *(uint4*)&o[0];
      *(uint4*)&dst[8] = *(uint4*)&o[8];
    }
  }
  __syncthreads();
  // subtree-sum pyramid, fused pairs {5,4},{3,2},{1,0}; agg -> ah(+0).
  // Convention: S(node n) stored at slot (2n-1). inv(lv)=1/(2^(7-lv)-2).
  {
    for (int idx = tid; idx < 16 * 32; idx += NT) {
      int k = 16 + (idx >> 5), j = idx & 31;
      floatx4 sa = smv[(4 * k - 1) * 32 + j] + smv[(4 * k) * 32 + j];
      floatx4 sc = smv[(4 * k + 1) * 32 + j] + smv[(4 * k + 2) * 32 + j];
      floatx4 sk = (smv[(2 * k - 1) * 32 + j] + smv[(2 * k) * 32 + j]) + (sa + sc);
      smv[(4 * k - 1) * 32 + j] = sa;
      smv[(4 * k + 1) * 32 + j] = sc;
      smv[(2 * k - 1) * 32 + j] = sk;
      st_agg(ah, b, ((16 + s) << 5) | (2 * k - 32), j, sa, 0.5f);
      st_agg(ah, b, ((16 + s) << 5) | (2 * k + 1 - 32), j, sc, 0.5f);
      st_agg(ah, b, ((16 + s) << 4) | (k - 16), j, sk, 1.0f / 6.0f);
    }
    __syncthreads();
    for (int idx = tid; idx < 4 * 32; idx += NT) {
      int k = 4 + (idx >> 5), j = idx & 31;
      floatx4 sa = (smv[(4 * k - 1) * 32 + j] + smv[(4 * k) * 32 + j]) +
                   (smv[(8 * k - 1) * 32 + j] + smv[(8 * k + 1) * 32 + j]);
      floatx4 sc = (smv[(4 * k + 1) * 32 + j] + smv[(4 * k + 2) * 32 + j]) +
                   (smv[(8 * k + 3) * 32 + j] + smv[(8 * k + 5) * 32 + j]);
      floatx4 sk = (smv[(2 * k - 1) * 32 + j] + smv[(2 * k) * 32 + j]) + (sa + sc);
      smv[(4 * k - 1) * 32 + j] = sa;
      smv[(4 * k + 1) * 32 + j] = sc;
      smv[(2 * k - 1) * 32 + j] = sk;
      st_agg(ah, b, ((16 + s) << 3) | (2 * k - 8), j, sa, 1.0f / 14.0f);
      st_agg(ah, b, ((16 + s) << 3) | (2 * k + 1 - 8), j, sc, 1.0f / 14.0f);
      st_agg(ah, b, ((16 + s) << 2) | (k - 4), j, sk, 1.0f / 30.0f);
    }
    __syncthreads();
    for (int idx = tid; idx < 32; idx += NT) {
      int j = idx;
      floatx4 sa = (smv[3 * 32 + j] + smv[4 * 32 + j]) +
                   (smv[7 * 32 + j] + smv[9 * 32 + j]);
      floatx4 sc = (smv[5 * 32 + j] + smv[6 * 32 + j]) +
                   (smv[11 * 32 + j] + smv[13 * 32 + j]);
      floatx4 sk = (smv[1 * 32 + j] + smv[2 * 32 + j]) + (sa + sc);
      st_agg(ah, b, ((16 + s) << 1) | 0, j, sa, 1.0f / 62.0f);
      st_agg(ah, b, ((16 + s) << 1) | 1, j, sc, 1.0f / 62.0f);
      st_agg(ah, b, (16 + s), j, sk, 1.0f / 126.0f);
      ((floatx4*)&sroot[(size_t)(b * 16 + s) * DD])[j] = sk;
    }
  }
  // gbar0's syncthreads covers the tail
}

// ---------------------------------------------------------------------------
// Top nodes 0..15: x0 into LDS xs, layer-0 h -> ah.
__device__ __forceinline__ void ph_top(char* smemc, int b,
                                       const float* __restrict__ lvl4,
                                       unsigned short* __restrict__ ah,
                                       const float* __restrict__ gamma,
                                       const float* __restrict__ beta) {
  float (*xs)[DD] = (float(*)[DD])smemc;      // 8 KB
  int tid = threadIdx.x;
  if (tid < 128) {
    int d = tid;
    float v[16];
    for (int j = 0; j < 16; ++j) v[j] = lvl4[(b * 16 + j) * DD + d];
    for (int j = 0; j < 8; ++j) v[j] = 0.5f * (v[2 * j] + v[2 * j + 1]);
    for (int j = 0; j < 8; ++j) xs[8 + j][d] = v[j] + enc_val(8 + j, d);
    for (int j = 0; j < 4; ++j) v[j] = 0.5f * (v[2 * j] + v[2 * j + 1]);
    for (int j = 0; j < 4; ++j) xs[4 + j][d] = v[j] + enc_val(4 + j, d);
    for (int j = 0; j < 2; ++j) v[j] = 0.5f * (v[2 * j] + v[2 * j + 1]);
    for (int j = 0; j < 2; ++j) xs[2 + j][d] = v[j] + enc_val(2 + j, d);
    v[0] = 0.5f * (v[0] + v[1]);
    xs[1][d] = v[0] + enc_val(1, d);
    xs[0][d] = -1.0f + enc_val(0, d);
  }
  __syncthreads();
  if (tid < 128) {
    int rr = tid >> 3, sub = tid & 7, dp = sub * 16;
    float w[16], s1 = 0.f, s2 = 0.f;
#pragma unroll
    for (int j = 0; j < 16; ++j) { w[j] = xs[rr][dp + j]; s1 += w[j]; s2 += w[j] * w[j]; }
    s1 += __shfl_xor(s1, 1); s2 += __shfl_xor(s2, 1);
    s1 += __shfl_xor(s1, 2); s2 += __shfl_xor(s2, 2);
    s1 += __shfl_xor(s1, 4); s2 += __shfl_xor(s2, 4);
    float mu = s1 * (1.0f / 128.0f);
    float var = s2 * (1.0f / 128.0f) - mu * mu;
    float rinv = rsqrtf(var + 1e-5f);
    __attribute__((aligned(16))) unsigned short o[16];
#pragma unroll
    for (int j = 0; j < 16; ++j)
      o[j] = f2bf(gelu((w[j] - mu) * rinv * gamma[dp + j] + beta[dp + j]));
    unsigned short* dst = &ah[(size_t)(b * NN + rr) * AHS + 128 + dp];
    *(uint4*)&dst[0] = *(uint4*)&o[0];
    *(uint4*)&dst[8] = *(uint4*)&o[8];
  }
  __syncthreads();
}

// ---------------------------------------------------------------------------
// Subtree sums for L1: reads h' from ah(+256), agg -> ah(+0), sroot.
// Fused level pairs {4,3},{2,1},{0}: 3 internal barriers.
__device__ __forceinline__ void ph_aggsub(char* smemc, int b, int s,
                                          unsigned short* ah,
                                          float* __restrict__ sroot) {
  floatx4 (*S)[32] = (floatx4(*)[32])smemc;   // 32 KB
  int tid = threadIdx.x;
  for (int idx = tid; idx < 32 * 32; idx += NT) {
    int k = 32 + (idx >> 5), q = idx & 31;
    int c = (16 + s) * 64 + (2 * k - 64);
    size_t a0 = (size_t)(b * NN + c) * AHS + 256 + q * 4;
    ushort4 u0 = *(const ushort4*)&ah[a0];
    ushort4 u1 = *(const ushort4*)&ah[a0 + AHS];
    floatx4 v;
    v[0] = bf2f(u0.x) + bf2f(u1.x);
    v[1] = bf2f(u0.y) + bf2f(u1.y);
    v[2] = bf2f(u0.z) + bf2f(u1.z);
    v[3] = bf2f(u0.w) + bf2f(u1.w);
    S[k][q] = v;
    st_agg(ah, b, (16 + s) * 32 + (k - 32), q, v, 0.5f);
  }
  __syncthreads();
  // {4,3}: per lv3 node k=8..15
  for (int idx = tid; idx < 8 * 32; idx += NT) {
    int k = 8 + (idx >> 5), q = idx & 31;
    size_t aa = (size_t)(b * NN + (((16 + s) << 5) | (4 * k - 32))) * AHS + 256 + q * 4;
    ushort4 u0 = *(const ushort4*)&ah[aa];
    ushort4 u1 = *(const ushort4*)&ah[aa + AHS];
    size_t ab = (size_t)(b * NN + (((16 + s) << 5) | (4 * k + 2 - 32))) * AHS + 256 + q * 4;
    ushort4 w0 = *(const ushort4*)&ah[ab];
    ushort4 w1 = *(const ushort4*)&ah[ab + AHS];
    size_t ac = (size_t)(b * NN + (((16 + s) << 4) | (2 * k - 16))) * AHS + 256 + q * 4;
    ushort4 h0 = *(const ushort4*)&ah[ac];
    ushort4 h1 = *(const ushort4*)&ah[ac + AHS];
    floatx4 s4a, s4b, s3;
    floatx4 sc0 = S[4 * k][q], sc1 = S[4 * k + 1][q];
    floatx4 sd0 = S[4 * k + 2][q], sd1 = S[4 * k + 3][q];
    s4a[0] = bf2f(u0.x) + bf2f(u1.x) + sc0[0] + sc1[0];
    s4a[1] = bf2f(u0.y) + bf2f(u1.y) + sc0[1] + sc1[1];
    s4a[2] = bf2f(u0.z) + bf2f(u1.z) + sc0[2] + sc1[2];
    s4a[3] = bf2f(u0.w) + bf2f(u1.w) + sc0[3] + sc1[3];
    s4b[0] = bf2f(w0.x) + bf2f(w1.x) + sd0[0] + sd1[0];
    s4b[1] = bf2f(w0.y) + bf2f(w1.y) + sd0[1] + sd1[1];
    s4b[2] = bf2f(w0.z) + bf2f(w1.z) + sd0[2] + sd1[2];
    s4b[3] = bf2f(w0.w) + bf2f(w1.w) + sd0[3] + sd1[3];
    s3[0] = bf2f(h0.x) + bf2f(h1.x) + s4a[0] + s4b[0];
    s3[1] = bf2f(h0.y) + bf2f(h1.y) + s4a[1] + s4b[1];
    s3[2] = bf2f(h0.z) + bf2f(h1.z) + s4a[2] + s4b[2];
    s3[3] = bf2f(h0.w) + bf2f(h1.w) + s4a[3] + s4b[3];
    S[2 * k][q] = s4a; S[2 * k + 1][q] = s4b; S[k][q] = s3;
    st_agg(ah, b, ((16 + s) << 4) | (2 * k - 16), q, s4a, 1.0f / 6.0f);
    st_agg(ah, b, ((16 + s) << 4) | (2 * k + 1 - 16), q, s4b, 1.0f / 6.0f);
    st_agg(ah, b, ((16 + s) << 3) | (k - 8), q, s3, 1.0f / 14.0f);
  }
  __syncthreads();
  // {2,1}: per lv1 node k=2..3
  for (int idx = tid; idx < 2 * 32; idx += NT) {
    int k = 2 + (idx >> 5), q = idx & 31;
    size_t aa = (size_t)(b * NN + (((16 + s) << 3) | (4 * k - 8))) * AHS + 256 + q * 4;
    ushort4 u0 = *(const ushort4*)&ah[aa];
    ushort4 u1 = *(const ushort4*)&ah[aa + AHS];
    size_t ab = (size_t)(b * NN + (((16 + s) << 3) | (4 * k + 2 - 8))) * AHS + 256 + q * 4;
    ushort4 w0 = *(const ushort4*)&ah[ab];
    ushort4 w1 = *(const ushort4*)&ah[ab + AHS];
    size_t ac = (size_t)(b * NN + (((16 + s) << 2) | (2 * k - 4))) * AHS + 256 + q * 4;
    ushort4 h0 = *(const ushort4*)&ah[ac];
    ushort4 h1 = *(const ushort4*)&ah[ac + AHS];
    floatx4 s2a, s2b, s1v;
    floatx4 sc0 = S[4 * k][q], sc1 = S[4 * k + 1][q];
    floatx4 sd0 = S[4 * k + 2][q], sd1 = S[4 * k + 3][q];
    s2a[0] = bf2f(u0.x) + bf2f(u1.x) + sc0[0] + sc1[0];
    s2a[1] = bf2f(u0.y) + bf2f(u1.y) + sc0[1] + sc1[1];
    s2a[2] = bf2f(u0.z) + bf2f(u1.z) + sc0[2] + sc1[2];
    s2a[3] = bf2f(u0.w) + bf2f(u1.w) + sc0[3] + sc1[3];
    s2b[0] = bf2f(w0.x) + bf2f(w1.x) + sd0[0] + sd1[0];
    s2b[1] = bf2f(w0.y) + bf2f(w1.y) + sd0[1] + sd1[1];
    s2b[2] = bf2f(w0.z) + bf2f(w1.z) + sd0[2] + sd1[2];
    s2b[3] = bf2f(w0.w) + bf2f(w1.w) + sd0[3] + sd1[3];
    s1v[0] = bf2f(h0.x) + bf2f(h1.x) + s2a[0] + s2b[0];
    s1v[1] = bf2f(h0.y) + bf2f(h1.y) + s2a[1] + s2b[1];
    s1v[2] = bf2f(h0.z) + bf2f(h1.z) + s2a[2] + s2b[2];
    s1v[3] = bf2f(h0.w) + bf2f(h1.w) + s2a[3] + s2b[3];
    S[2 * k][q] = s2a; S[2 * k + 1][q] = s2b; S[k][q] = s1v;
    st_agg(ah, b, ((16 + s) << 2) | (2 * k - 4), q, s2a, 1.0f / 30.0f);
    st_agg(ah, b, ((16 + s) << 2) | (2 * k + 1 - 4), q, s2b, 1.0f / 30.0f);
    st_agg(ah, b, ((16 + s) << 1) | (k - 2), q, s1v, 1.0f / 62.0f);
  }
  __syncthreads();
  // {0}: root of subtree; sroot written directly from registers
  for (int idx = tid; idx < 32; idx += NT) {
    int q = idx;
    size_t aa = (size_t)(b * NN + (((16 + s) << 1) | 0)) * AHS + 256 + q * 4;
    ushort4 u0 = *(const ushort4*)&ah[aa];
    ushort4 u1 = *(const ushort4*)&ah[aa + AHS];
    floatx4 sc0 = S[2][q], sc1 = S[3][q];
    floatx4 s0v;
    s0v[0] = bf2f(u0.x) + bf2f(u1.x) + sc0[0] + sc1[0];
    s0v[1] = bf2f(u0.y) + bf2f(u1.y) + sc0[1] + sc1[1];
    s0v[2] = bf2f(u0.z) + bf2f(u1.z) + sc0[2] + sc1[2];
    s0v[3] = bf2f(u0.w) + bf2f(u1.w) + sc0[3] + sc1[3];
    st_agg(ah, b, (16 + s), q, s0v, 1.0f / 126.0f);
    ((floatx4*)sroot)[(size_t)(b * 16 + s) * 32 + q] = s0v;
  }
}

// ---------------------------------------------------------------------------
// MFMA leaf gather, single-pass: agg(32x128) = onehot * H, K<=224 staged into
// the full SB fragment buffer. Selector = 1 KB bitmask expanded to A-fragment
// in registers. msk/invdeg/fb persist across layers (build=1 only in P1).
// 3 internal barriers; caller adds one after return before reading aggl.
__device__ __forceinline__ void ph_leafagg(char* smemc, int b, int jb,
                                           const int* __restrict__ srcv,
                                           const int* __restrict__ dstv,
                                           const int* __restrict__ s0a,
                                           const int* __restrict__ s1a,
                                           const unsigned short* __restrict__ eoff,
                                           unsigned short* ah, int hoff,
                                           int build) {
  int tid = threadIdx.x;
  int lane = tid & 63, wv = tid >> 6;
  unsigned short* SB = (unsigned short*)(smemc + SB_OFF);
  unsigned* msk = (unsigned*)(smemc + MSK_OFF);
  float* invdeg = (float*)(smemc + DEG_OFF);
  unsigned int* fb = (unsigned int*)(smemc + FB_OFF);
  unsigned short* aggl = (unsigned short*)(smemc + AGGL_OFF);
  int rbase = b * NN + 1024 + jb * 32;

  int lo[11], wd[11], off[11];
  int acc_off = 0;
#pragma unroll
  for (int cd = 10; cd >= 1; --cd) {
    win_cd(jb, cd, lo[cd], wd[cd]);
    off[cd] = acc_off;
    acc_off += wd[cd];
  }

  // phase Z: zero SB (58240 B); on build also zero msk, set invdeg, fb
  for (int t = tid; t < 3640; t += NT)
    ((uint4*)smemc)[t] = make_uint4(0, 0, 0, 0);
  if (build) {
    if (tid < 256) msk[tid] = 0u;
    if (tid >= 256 && tid < 288)
      invdeg[tid - 256] = 1.0f /
          (float)max(s1a[rbase + tid - 256] - s0a[rbase + tid - 256], 1);
    if (tid == 288) *fb = 0u;
  }
  __syncthreads();                                             // B1

  // build selector bitmask (P1 only) + stage H rows into SB frag layout
  if (build) {
    int E0 = s0a[rbase], E1 = s1a[rbase + 31];
    for (int e = E0 + tid; e < E1; e += NT) {
      int leaf = dstv[e] - rbase;
      unsigned kr = eoff[e];
      if (kr == 0xFFFFu) atomicOr(fb, 1u << leaf);
      else atomicOr(&msk[leaf * 8 + (kr >> 5)], 1u << (kr & 31));
    }
  }
#pragma unroll
  for (int cd = 10; cd >= 1; --cd) {
    int w = wd[cd];
    for (int t = tid; t < w * 16; t += NT) {
      int row = t >> 4, seg = t & 15;
      int kr = off[cd] + row;
      uint4 u = *(const uint4*)&ah[(size_t)(b * NN + lo[cd] + row) * AHS + hoff + seg * 8];
      unsigned short* p = SB + ((kr >> 5) * 8 + (seg >> 1)) * SBT +
                          ((kr & 31) >> 3) * 128 + (seg & 1) * 64 + (kr & 7);
      p[0]  = (unsigned short)(u.x & 0xffff);
      p[8]  = (unsigned short)(u.x >> 16);
      p[16] = (unsigned short)(u.y & 0xffff);
      p[24] = (unsigned short)(u.y >> 16);
      p[32] = (unsigned short)(u.z & 0xffff);
      p[40] = (unsigned short)(u.z >> 16);
      p[48] = (unsigned short)(u.w & 0xffff);
      p[56] = (unsigned short)(u.w >> 16);
    }
  }
  __syncthreads();                                             // B2

  // MFMA: 7 K-chunks, A built from bitmask in registers
  int m = lane & 15, q = lane >> 4;
  int mt = wv >> 3, nt = wv & 7;
  int arow = mt * 16 + m;
  floatx4 acc = (floatx4){0.f, 0.f, 0.f, 0.f};
#pragma unroll
  for (int kcl = 0; kcl < 7; ++kcl) {
    unsigned mw = msk[arow * 8 + kcl];
    unsigned bits = (mw >> (q * 8)) & 0xffu;
    union { uint4 u; bf16x8 v; } A;
    A.u.x = ((bits & 1u)  ? 0x3F80u : 0u) | ((bits & 2u)   ? 0x3F800000u : 0u);
    A.u.y = ((bits & 4u)  ? 0x3F80u : 0u) | ((bits & 8u)   ? 0x3F800000u : 0u);
    A.u.z = ((bits & 16u) ? 0x3F80u : 0u) | ((bits & 32u)  ? 0x3F800000u : 0u);
    A.u.w = ((bits & 64u) ? 0x3F80u : 0u) | ((bits & 128u) ? 0x3F800000u : 0u);
    bf16x8 bb = *(const bf16x8*)&SB[(kcl * 8 + nt) * SBT + lane * 8];
    acc = __builtin_amdgcn_mfma_f32_16x16x32_bf16(A.v, bb, acc, 0, 0, 0);
  }
  __syncthreads();                                             // B3 (SB dead)

  unsigned fbm = *fb;
#pragma unroll
  for (int r = 0; r < 4; ++r) {
    int leaf = mt * 16 + q * 4 + r;
    if (!((fbm >> leaf) & 1u))
      aggl[leaf * CSTRIDE + nt * 16 + m] = f2bf(acc[r] * invdeg[leaf]);
  }
  // safety net: out-of-window edges (never expected) -> scalar full redo
  if (fbm && tid < 512) {
    int leaf = tid >> 4, c = tid & 15;
    if ((fbm >> leaf) & 1u) {
      int e0 = s0a[rbase + leaf], e1 = s1a[rbase + leaf];
      floatx2 a0 = {0.f, 0.f}, a1 = {0.f, 0.f}, a2 = {0.f, 0.f}, a3 = {0.f, 0.f};
      for (int e = e0; e < e1; ++e) {
        int g = srcv[e] - b * NN;
        uint4 u = *(const uint4*)&ah[(size_t)(b * NN + g) * AHS + hoff + c * 8];
        a0 += bfpair(u.x); a1 += bfpair(u.y); a2 += bfpair(u.z); a3 += bfpair(u.w);
      }
      float inv = 1.0f / (float)max(e1 - e0, 1);
      __attribute__((aligned(16))) unsigned short o[8];
      o[0] = f2bf(a0[0] * inv); o[1] = f2bf(a0[1] * inv);
      o[2] = f2bf(a1[0] * inv); o[3] = f2bf(a1[1] * inv);
      o[4] = f2bf(a2[0] * inv); o[5] = f2bf(a2[1] * inv);
      o[6] = f2bf(a3[0] * inv); o[7] = f2bf(a3[1] * inv);
      *(uint4*)&aggl[leaf * CSTRIDE + c * 8] = *(uint4*)&o[0];
    }
  }
}

// ---------------------------------------------------------------------------
// Finish agg for nodes 0..15 (tid<128); h at +hoff, closed-form deg.
__device__ __forceinline__ void ph_topfin(int b,
                                          const float* __restrict__ sroot,
                                          unsigned short* ah, int hoff) {
  int d = threadIdx.x;
  float S16[16], h16[16], Sv[16];
#pragma unroll
  for (int j = 0; j < 16; ++j) S16[j] = sroot[(size_t)(b * 16 + j) * DD + d];
#pragma unroll
  for (int j = 0; j < 16; ++j)
    h16[j] = bf2f(ah[(size_t)(b * NN + 16 + j) * AHS + hoff + d]);
#pragma unroll
  for (int k = 8; k < 16; ++k)
    Sv[k] = h16[2 * k - 16] + h16[2 * k - 15] + S16[2 * k - 16] + S16[2 * k - 15];
#pragma unroll
  for (int k = 7; k >= 1; --k)
    Sv[k] = bf2f(ah[(size_t)(b * NN + 2 * k) * AHS + hoff + d]) +
            bf2f(ah[(size_t)(b * NN + 2 * k + 1) * AHS + hoff + d]) +
            Sv[2 * k] + Sv[2 * k + 1];
#pragma unroll
  for (int k = 1; k < 16; ++k) {
    int dv = 31 - __clz(k);
    float inv = 1.0f / (float)((1 << (11 - dv)) - 2);
    ah[(size_t)(b * NN + k) * AHS + d] = f2bf(Sv[k] * inv);
  }
  ah[(size_t)(b * NN) * AHS + d] = f2bf(0.0f);
}

// ---------------------------------------------------------------------------
// 32-row leaf GEMM tile (contiguous rows at rowbase). agg A-operand (kc<4)
// from the aggl LDS buffer. Runs on waves 0-7 (concurrently with ph_gemm32s
// on waves 8-15); exactly 2 __syncthreads when first_layer, else 0.
__device__ __forceinline__ void ph_gemm32(char* redc, const unsigned short* aggl,
                                          int rowbase, unsigned short* ah,
                                          const unsigned short* __restrict__ wfl,
                                          const float* __restrict__ bn,
                                          float* __restrict__ x, int hoff_in,
                                          const float* __restrict__ gamma,
                                          const float* __restrict__ beta,
                                          float* xc, int first_layer) {
  int wave = threadIdx.x >> 6, lane = threadIdx.x & 63;
  bool act = wave < 8;
  int wl = wave & 7;
  int mt = wl >> 2, nq = wl & 3;
  int r0 = rowbase + mt * 16;
  int m = lane & 15, q = lane >> 4;
  floatx4 acc[2];
  acc[0] = (floatx4){0.f, 0.f, 0.f, 0.f};
  acc[1] = (floatx4){0.f, 0.f, 0.f, 0.f};
  if (act) {
    const unsigned short* arow = ah + (size_t)(r0 + m) * AHS + q * 8;
    const bf16x8* B = (const bf16x8*)wfl + lane;
#pragma unroll
    for (int kc = 0; kc < 8; ++kc) {
      bf16x8 a0;
      if (kc < 4)
        a0 = *(const bf16x8*)&aggl[(mt * 16 + m) * CSTRIDE + kc * 32 + q * 8];
      else
        a0 = *(const bf16x8*)(arow + hoff_in + (kc - 4) * 32);
#pragma unroll
      for (int ci = 0; ci < 2; ++ci) {
        bf16x8 bb = B[(kc * 8 + nq * 2 + ci) * 64];
        acc[ci] = __builtin_amdgcn_mfma_f32_16x16x32_bf16(a0, bb, acc[ci], 0, 0, 0);
      }
    }
  }
  if (first_layer) {
    float s1[4] = {0.f, 0.f, 0.f, 0.f}, s2[4] = {0.f, 0.f, 0.f, 0.f};
    if (act) {
#pragma unroll
      for (int ci = 0; ci < 2; ++ci) {
        int col = (nq * 2 + ci) * 16 + m;
        float bias = bn[col];
#pragma unroll
        for (int r = 0; r < 4; ++r) {
          int row = r0 + q * 4 + r;
          float v = x[(size_t)row * DD + col] + acc[ci][r] + bias;
          xc[ci * 4 + r] = v;
          s1[r] += v; s2[r] += v * v;
        }
      }
#pragma unroll
      for (int r = 0; r < 4; ++r) {
        s1[r] += __shfl_xor(s1[r], 1); s2[r] += __shfl_xor(s2[r], 1);
        s1[r] += __shfl_xor(s1[r], 2); s2[r] += __shfl_xor(s2[r], 2);
        s1[r] += __shfl_xor(s1[r], 4); s2[r] += __shfl_xor(s2[r], 4);
        s1[r] += __shfl_xor(s1[r], 8); s2[r] += __shfl_xor(s2[r], 8);
      }
    }
    float* red = (float*)redc;
    int rl = mt * 16 + q * 4;
    __syncthreads();
    if (act && m == 0) {
#pragma unroll
      for (int r = 0; r < 4; ++r) {
        red[(rl + r) * 4 + nq] = s1[r];
        red[128 + (rl + r) * 4 + nq] = s2[r];
      }
    }
    __syncthreads();
    if (act) {
      float mu[4], rv[4];
#pragma unroll
      for (int r = 0; r < 4; ++r) {
        float t1 = red[(rl + r) * 4] + red[(rl + r) * 4 + 1] +
                   red[(rl + r) * 4 + 2] + red[(rl + r) * 4 + 3];
        float t2 = red[128 + (rl + r) * 4] + red[128 + (rl + r) * 4 + 1] +
                   red[128 + (rl + r) * 4 + 2] + red[128 + (rl + r) * 4 + 3];
        mu[r] = t1 * (1.0f / 128.0f);
        float var = t2 * (1.0f / 128.0f) - mu[r] * mu[r];
        rv[r] = rsqrtf(var + 1e-5f);
      }
#pragma unroll
      for (int ci = 0; ci < 2; ++ci) {
        int col = (nq * 2 + ci) * 16 + m;
        float gm = gamma[col], bt = beta[col];
#pragma unroll
        for (int r = 0; r < 4; ++r) {
          int row = r0 + q * 4 + r;
          float hh = gelu((xc[ci * 4 + r] - mu[r]) * rv[r] * gm + bt);
          ah[(size_t)row * AHS + 256 + col] = f2bf(hh);
        }
      }
    }
  } else {
    if (act) {
#pragma unroll
      for (int ci = 0; ci < 2; ++ci) {
        int col = (nq * 2 + ci) * 16 + m;
        float bias = bn[col];
#pragma unroll
        for (int r = 0; r < 4; ++r) {
          int row = r0 + q * 4 + r;
          x[(size_t)row * DD + col] = xc[ci * 4 + r] + acc[ci][r] + bias;
        }
      }
    }
  }
}

// ---------------------------------------------------------------------------
// 32-row internal GEMM tile with SCATTERED rows. Runs on waves 8-15.
// first_layer residual: from gx (global x0) when gx != nullptr, else xc.
// Exactly 2 __syncthreads when first_layer, else 0 (matches ph_gemm32).
__device__ __forceinline__ void ph_gemm32s(char* redc, int b, int sb, int tbase,
                                           unsigned short* ah,
                                           const unsigned short* __restrict__ wfl,
                                           const float* __restrict__ bn,
                                           float* __restrict__ x, int hoff_in,
                                           const float* __restrict__ gamma,
                                           const float* __restrict__ beta,
                                           float* xc, int first_layer,
                                           const float* __restrict__ gx) {
  int wave = threadIdx.x >> 6, lane = threadIdx.x & 63;
  bool act = wave >= 8;
  int wl = wave & 7;
  int mt = wl >> 2, nq = wl & 3;
  int m = lane & 15, q = lane >> 4;
  int tA = tbase + mt * 16 + m;
  int kA = (tA == 63) ? 1 : tA + 1;
  int lvA = 31 - __clz(kA);
  int rowA = b * NN + (((16 + sb) << lvA) | (kA - (1 << lvA)));
  int rowO[4];
#pragma unroll
  for (int r = 0; r < 4; ++r) {
    int t = tbase + mt * 16 + q * 4 + r;
    int k = (t == 63) ? 1 : t + 1;
    int lv = 31 - __clz(k);
    rowO[r] = b * NN + (((16 + sb) << lv) | (k - (1 << lv)));
  }
  floatx4 acc[2];
  acc[0] = (floatx4){0.f, 0.f, 0.f, 0.f};
  acc[1] = (floatx4){0.f, 0.f, 0.f, 0.f};
  if (act) {
    const unsigned short* arow = ah + (size_t)rowA * AHS + q * 8;
    const bf16x8* B = (const bf16x8*)wfl + lane;
#pragma unroll
    for (int kc = 0; kc < 8; ++kc) {
      int koff = (kc < 4) ? kc * 32 : hoff_in + (kc - 4) * 32;
      bf16x8 a0 = *(const bf16x8*)(arow + koff);
#pragma unroll
      for (int ci = 0; ci < 2; ++ci) {
        bf16x8 bb = B[(kc * 8 + nq * 2 + ci) * 64];
        acc[ci] = __builtin_amdgcn_mfma_f32_16x16x32_bf16(a0, bb, acc[ci], 0, 0, 0);
      }
    }
  }
  if (first_layer) {
    float s1[4] = {0.f, 0.f, 0.f, 0.f}, s2[4] = {0.f, 0.f, 0.f, 0.f};
    if (act) {
#pragma unroll
      for (int ci = 0; ci < 2; ++ci) {
        int col = (nq * 2 + ci) * 16 + m;
        float bias = bn[col];
#pragma unroll
        for (int r = 0; r < 4; ++r) {
          float x0 = gx ? gx[(size_t)rowO[r] * DD + col] : xc[ci * 4 + r];
          float v = x0 + acc[ci][r] + bias;
          xc[ci * 4 + r] = v;
          s1[r] += v; s2[r] += v * v;
        }
      }
#pragma unroll
      for (int r = 0; r < 4; ++r) {
        s1[r] += __shfl_xor(s1[r], 1); s2[r] += __shfl_xor(s2[r], 1);
        s1[r] += __shfl_xor(s1[r], 2); s2[r] += __shfl_xor(s2[r], 2);
        s1[r] += __shfl_xor(s1[r], 4); s2[r] += __shfl_xor(s2[r], 4);
        s1[r] += __shfl_xor(s1[r], 8); s2[r] += __shfl_xor(s2[r], 8);
      }
    }
    float* red = (float*)redc;
    int rl = mt * 16 + q * 4;
    __syncthreads();
    if (act && m == 0) {
#pragma unroll
      for (int r = 0; r < 4; ++r) {
        red[(rl + r) * 4 + nq] = s1[r];
        red[128 + (rl + r) * 4 + nq] = s2[r];
      }
    }
    __syncthreads();
    if (act) {
      float mu[4], rv[4];
#pragma unroll
      for (int r = 0; r < 4; ++r) {
        float t1 = red[(rl + r) * 4] + red[(rl + r) * 4 + 1] +
                   red[(rl + r) * 4 + 2] + red[(rl + r) * 4 + 3];
        float t2 = red[128 + (rl + r) * 4] + red[128 + (rl + r) * 4 + 1] +
                   red[128 + (rl + r) * 4 + 2] + red[128 + (rl + r) * 4 + 3];
        mu[r] = t1 * (1.0f / 128.0f);
        float var = t2 * (1.0f / 128.0f) - mu[r] * mu[r];
        rv[r] = rsqrtf(var + 1e-5f);
      }
#pragma unroll
      for (int ci = 0; ci < 2; ++ci) {
        int col = (nq * 2 + ci) * 16 + m;
        float gm = gamma[col], bt = beta[col];
#pragma unroll
        for (int r = 0; r < 4; ++r) {
          float hh = gelu((xc[ci * 4 + r] - mu[r]) * rv[r] * gm + bt);
          ah[(size_t)rowO[r] * AHS + 256 + col] = f2bf(hh);
        }
      }
    }
  } else {
    if (act) {
#pragma unroll
      for (int ci = 0; ci < 2; ++ci) {
        int col = (nq * 2 + ci) * 16 + m;
        float bias = bn[col];
#pragma unroll
        for (int r = 0; r < 4; ++r)
          x[(size_t)rowO[r] * DD + col] = xc[ci * 4 + r] + acc[ci][r] + bias;
      }
    }
  }
}

// ---------------------------------------------------------------------------
// 16-row top GEMM tile (rows 0..15 of batch b). Waves 0-7 = 8 col-tiles;
// waves 8-15 inactive. Called by ALL waves (runs alone, not concurrent).
__device__ __forceinline__ void ph_gemm16t(char* redc, int b,
                                           unsigned short* ah,
                                           const unsigned short* __restrict__ wfl,
                                           const float* __restrict__ bn,
                                           float* __restrict__ x, int hoff_in,
                                           const float* __restrict__ gamma,
                                           const float* __restrict__ beta,
                                           float* xc, int first_layer) {
  int ct = threadIdx.x >> 6, lane = threadIdx.x & 63;
  bool act = ct < 8;
  int m = lane & 15, q = lane >> 4;
  floatx4 acc = (floatx4){0.f, 0.f, 0.f, 0.f};
  int col = (ct & 7) * 16 + m;
  if (act) {
    const unsigned short* arow = ah + (size_t)(b * NN + m) * AHS + q * 8;
    const bf16x8* B = (const bf16x8*)wfl + lane;
#pragma unroll
    for (int kc = 0; kc < 8; ++kc) {
      int koff = (kc < 4) ? kc * 32 : hoff_in + (kc - 4) * 32;
      bf16x8 a0 = *(const bf16x8*)(arow + koff);
      bf16x8 bb = B[(kc * 8 + ct) * 64];
      acc = __builtin_amdgcn_mfma_f32_16x16x32_bf16(a0, bb, acc, 0, 0, 0);
    }
  }
  if (first_layer) {
    float s1[4] = {0.f, 0.f, 0.f, 0.f}, s2[4] = {0.f, 0.f, 0.f, 0.f};
    float bias = act ? bn[col] : 0.f;
    if (act) {
#pragma unroll
      for (int r = 0; r < 4; ++r) {
        float v = xc[r] + acc[r] + bias;
        xc[r] = v; s1[r] = v; s2[r] = v * v;
      }
#pragma unroll
      for (int r = 0; r < 4; ++r) {
        s1[r] += __shfl_xor(s1[r], 1); s2[r] += __shfl_xor(s2[r], 1);
        s1[r] += __shfl_xor(s1[r], 2); s2[r] += __shfl_xor(s2[r], 2);
        s1[r] += __shfl_xor(s1[r], 4); s2[r] += __shfl_xor(s2[r], 4);
        s1[r] += __shfl_xor(s1[r], 8); s2[r] += __shfl_xor(s2[r], 8);
      }
    }
    float* red = (float*)redc;
    __syncthreads();
    if (act && m == 0) {
#pragma unroll
      for (int r = 0; r < 4; ++r) {
        red[(q * 4 + r) * 8 + ct] = s1[r];
        red[128 + (q * 4 + r) * 8 + ct] = s2[r];
      }
    }
    __syncthreads();
    if (act) {
#pragma unroll
      for (int r = 0; r < 4; ++r) {
        float t1 = 0.f, t2 = 0.f;
#pragma unroll
        for (int j = 0; j < 8; ++j) {
          t1 += red[(q * 4 + r) * 8 + j];
          t2 += red[128 + (q * 4 + r) * 8 + j];
        }
        float mu = t1 * (1.0f / 128.0f);
        float var = t2 * (1.0f / 128.0f) - mu * mu;
        float rv = rsqrtf(var + 1e-5f);
        float hh = gelu((xc[r] - mu) * rv * gamma[col] + beta[col]);
        ah[(size_t)(b * NN + q * 4 + r) * AHS + 256 + col] = f2bf(hh);
      }
    }
  } else {
    if (act) {
      float bias = bn[col];
#pragma unroll
      for (int r = 0; r < 4; ++r)
        x[(size_t)(b * NN + q * 4 + r) * DD + col] = xc[r] + acc[r] + bias;
    }
  }
}

// ---------------------------------------------------------------------------
// Megakernel: 8 XCD-affine groups x 32 blocks (group = bid&7 = batch).
// gb 0-15: tree + t32 tile. gb 16-31: t0 tile of subtree gb-16.
// gb 16-23: CSR + eoff precompute. gb 24-27: weight repack. gb 28: top chain.
__global__ __launch_bounds__(NT, 1) void k_mega(
    const float* __restrict__ elements, const float* __restrict__ ln_gamma,
    const float* __restrict__ ln_beta, const float* __restrict__ w_nei,
    const float* __restrict__ b_nei, const float* __restrict__ w_root,
    const int* __restrict__ srcv, const int* __restrict__ dstv, int E,
    float* __restrict__ x, int* s0a, int* s1a, float* lvl4, float* sroot,
    unsigned short* wf, unsigned short* ah, unsigned short* eoff, int* bar) {
  __shared__ __align__(16) char smem[65536];
  int bid = blockIdx.x, tid = threadIdx.x;
  int b = bid & 7, gb = bid >> 3;    // XCD-affine: batch = bid % 8
  int Eb = E >> 3;
  unsigned short* wfg = wf + (size_t)b * 65536;
  float xcl[8], xci[8], xct[4];
  int wv = tid >> 6;

  // ---- P0 ----
  if (gb < 16) {
    ph_tree(smem, b, gb, elements, x, lvl4, ah, ln_gamma, ln_beta, sroot, xci, bar);
  } else if (gb < 24) {
    int base = b * Eb;
    for (int i = base + (gb - 16) * NT + tid; i < base + Eb; i += 8 * NT) {
      int dv = dstv[i];
      if (i == 0 || dstv[i - 1] != dv) s0a[dv] = i;
      if (i == base + Eb - 1 || dstv[i + 1] != dv) s1a[dv] = i + 1;
    }
    // precompute per-edge concatenated window ROW index for leaf-dst edges
    for (int i = base + (gb - 16) * NT + tid; i < base + Eb; i += 8 * NT) {
      int dl = dstv[i] - b * NN - 1024;
      unsigned short ov = 0xFFFFu;
      if (dl >= 0) {
        int jb2 = dl >> 5;
        int g = srcv[i] - b * NN;
        int lv = 31 - __clz(g);
        int acc2 = 0;
#pragma unroll
        for (int cd = 10; cd >= 1; --cd) {
          int lo_, wd_;
          win_cd(jb2, cd, lo_, wd_);
          if (cd == lv) {
            int idx = g - lo_;
            if ((unsigned)idx < (unsigned)wd_)
              ov = (unsigned short)(acc2 + idx);
          }
          acc2 += wd_;
        }
      }
      eoff[i] = ov;
    }
  } else if (gb < 28) {
    int gi = (gb - 24) * NT + tid;   // 0..4095 frag units
    int lane = gi & 63, ct = (gi >> 6) & 7, kc = gi >> 9;
    int n = ct * 16 + (lane & 15);
    int k = kc * 32 + (lane >> 4) * 8;
    int kk = k & 127;
#pragma unroll
    for (int l = 0; l < 2; ++l) {
      const float* w = (k < 128) ? (w_nei + (size_t)l * DD * DD)
                                 : (w_root + (size_t)l * DD * DD);
      unsigned short* o = wfg + (size_t)l * 32768 + (size_t)gi * 8;
#pragma unroll
      for (int j = 0; j < 8; ++j) o[j] = f2bf(w[(size_t)(kk + j) * DD + n]);
    }
  } else if (gb == 28) {
    // wait for all 16 lvl4 slices of this batch, then top-node x0 + h
    if (tid < 16) {
      while (!__hip_atomic_load(bar + 1536 + b * 64 + tid * 4, __ATOMIC_RELAXED,
                                __HIP_MEMORY_SCOPE_AGENT))
        __builtin_amdgcn_s_sleep(1);
      __threadfence();
    }
    __syncthreads();
    ph_top(smem, b, lvl4, ah, ln_gamma, ln_beta);  // xs in LDS, h0..15 -> ah
    {                                              // stash xct (waves 0-7)
      int ln = tid & 63, m_ = ln & 15, q_ = ln >> 4;
      if (wv < 8) {
        float (*xs)[DD] = (float(*)[DD])smem;
#pragma unroll
        for (int r = 0; r < 4; ++r) xct[r] = xs[q_ * 4 + r][wv * 16 + m_];
      }
    }
  }
  gbarN(bar, 0);

  // ---- P1 (layer 0) ----
  if (gb == 28) {
    if (tid < 128) ph_topfin(b, sroot, ah, 128);
    __syncthreads();
    ph_gemm16t(smem + RED_OFF, b, ah, wfg, b_nei, x, 128,
               ln_gamma + DD, ln_beta + DD, xct, 1);
    __syncthreads();
  }
  ph_leafagg(smem, b, gb, srcv, dstv, s0a, s1a, eoff, ah, 128, 1);
  __syncthreads();
  if (wv < 8) {
    ph_gemm32(smem + RED_OFF, (const unsigned short*)(smem + AGGL_OFF),
              b * NN + 1024 + gb * 32, ah, wfg, b_nei, x, 128,
              ln_gamma + DD, ln_beta + DD, xcl, 1);
  } else if (gb < 16) {
    ph_gemm32s(smem + RED2_OFF, b, gb, 32, ah, wfg, b_nei, x, 128,
               ln_gamma + DD, ln_beta + DD, xci, 1, nullptr);
  } else {
    ph_gemm32s(smem + RED2_OFF, b, gb - 16, 0, ah, wfg, b_nei, x, 128,
               ln_gamma + DD, ln_beta + DD, xci, 1, x);
  }
  gbarN(bar, 1);

  // ---- P2 (layer 1): no group barrier; per-subtree aggsub flags order the
  // agg(ah+0) producer (block s) against its consumers (block 16+s, gb28) ----
  if (gb < 16) {
    ph_aggsub(smem, b, gb, ah, sroot);
    __syncthreads();
    if (tid == 0) {
      __threadfence();
      __hip_atomic_store(bar + 1024 + b * 64 + gb * 4, 1, __ATOMIC_RELAXED,
                         __HIP_MEMORY_SCOPE_AGENT);
    }
  }
  ph_leafagg(smem, b, gb, srcv, dstv, s0a, s1a, eoff, ah, 256, 0);
  if (gb >= 16 && tid == 0) {
    // acquire subtree gb-16's aggsub output before the t0-tile gemm reads agg
    while (!__hip_atomic_load(bar + 1024 + b * 64 + (gb - 16) * 4, __ATOMIC_RELAXED,
                              __HIP_MEMORY_SCOPE_AGENT))
      __builtin_amdgcn_s_sleep(1);
    __threadfence();
  }
  __syncthreads();
  if (wv < 8) {
    ph_gemm32(smem + RED_OFF, (const unsigned short*)(smem + AGGL_OFF),
              b * NN + 1024 + gb * 32, ah, wfg + 32768, b_nei + DD,
              x, 256, ln_gamma, ln_beta, xcl, 0);
  } else if (gb < 16) {
    ph_gemm32s(smem + RED2_OFF, b, gb, 32, ah, wfg + 32768, b_nei + DD, x, 256,
               ln_gamma, ln_beta, xci, 0, nullptr);
  } else {
    ph_gemm32s(smem + RED2_OFF, b, gb - 16, 0, ah, wfg + 32768, b_nei + DD, x, 256,
               ln_gamma, ln_beta, xci, 0, nullptr);
  }
  if (gb == 28) {
    if (tid < 16) {
      while (!__hip_atomic_load(bar + 1024 + b * 64 + tid * 4, __ATOMIC_RELAXED,
                                __HIP_MEMORY_SCOPE_AGENT))
        __builtin_amdgcn_s_sleep(1);
      __threadfence();
    }
    __syncthreads();
    if (tid < 128) ph_topfin(b, sroot, ah, 256);
    __syncthreads();
    ph_gemm16t(smem + RED_OFF, b, ah, wfg + 32768, b_nei + DD, x, 256,
               ln_gamma, ln_beta, xct, 0);
  }
}

// ---------------------------------------------------------------------------
extern "C" void kernel_launch(void* const* d_in, const int* in_sizes, int n_in,
                              void* d_out, int out_size, void* d_ws, size_t ws_size,
                              hipStream_t stream) {
  const float* elements = (const float*)d_in[0];
  const float* ln_gamma = (const float*)d_in[1];
  const float* ln_beta  = (const float*)d_in[2];
  const float* w_nei    = (const float*)d_in[3];
  const float* b_nei    = (const float*)d_in[4];
  const float* w_root   = (const float*)d_in[5];
  const int*   edge     = (const int*)d_in[6];
  int E = in_sizes[6] / 2;
  const int* srcv = edge;
  const int* dstv = edge + E;
  float* x = (float*)d_out;

  char* ws = (char*)d_ws;
  int*            bar   = (int*)ws;                         // 8 KB used
  int*            s0    = (int*)(ws + 65536);               // 64 KB
  int*            s1    = (int*)(ws + 131072);              // 64 KB
  float*          lvl4  = (float*)(ws + 196608);            // 64 KB
  float*          sroot = (float*)(ws + 262144);            // 64 KB
  unsigned short* wf    = (unsigned short*)(ws + 327680);   // 1 MB (8 copies)
  unsigned short* ah    = (unsigned short*)(ws + 327680 + 1048576);  // 12.6 MB
  unsigned short* eoff  = (unsigned short*)(ws + 327680 + 1048576 + 12582912); // 2E B

  hipMemsetAsync(bar, 0, 8192, stream);
  k_mega<<<dim3(NB), dim3(NT), 0, stream>>>(
      elements, ln_gamma, ln_beta, w_nei, b_nei, w_root,
      srcv, dstv, E, x, s0, s1, lvl4, sroot, wf, ah, eoff, bar);
}

// Round 11
// 155.418 us; speedup vs baseline: 1.0695x; 1.0199x over previous
//
#include <hip/hip_runtime.h>
#include <hip/hip_bf16.h>

// Problem constants (fixed by the reference file)
#define LEAFN 1024
#define NN    2048            // nodes per batch incl. global node 0
#define BATCH 8
#define DD    128
#define ROWS  (BATCH*NN)      // 16384
#define AHS   384             // ah row stride: [agg(128) | hL0(128) | hL1(128)]
#define NB    256             // megakernel grid (1 block/CU)
#define NT    1024            // threads per block (16 waves)

// ln(10000)/32
#define LOG1E4_OVER_32 0.28782313662425575f

// window geometry; gather: agg(32x128) = onehot(32xK) * H(Kx128), K<=224
#define SLACK 9               // proven window coverage: drift <= 9 both sides
#define CSTRIDE 136           // aggl row stride in ushorts (gemm32 A-operand)
// LDS (static 64 KB):
//   SB  (B-frag buffer, 56 tiles x 520 u16)  @ 0     .. 58240
//   msk (selector bitmask, 32 rows x 8 u32)  @ 58240 .. 59264  [persists P1->P2]
//   invdeg (f32 x32)                         @ 59264 .. 59392  [persists]
//   fb (u32)                                 @ 59392            [persists]
//   aggl (32 x CSTRIDE u16)                  @ 0 (SB reuse after MFMA barrier)
//   red / red2 (LN scratch)                  @ 61440 / 62464 (.. 63488)
// msk/fb zeroed pre-gbar0 (disjoint from ph_tree's final phase / ph_top LDS).
#define SB_OFF   0
#define SBT      520          // u16 per B-frag tile (512 + 8 pad: bank spread)
#define MSK_OFF  58240
#define DEG_OFF  59264
#define FB_OFF   59392
#define AGGL_OFF 0
#define RED_OFF  61440
#define RED2_OFF 62464

typedef __bf16 bf16x8 __attribute__((ext_vector_type(8)));
typedef float  floatx4 __attribute__((ext_vector_type(4)));
typedef float  floatx2 __attribute__((ext_vector_type(2)));

__device__ __forceinline__ float bf2f(unsigned short u) {
  return __uint_as_float(((unsigned)u) << 16);
}
__device__ __forceinline__ unsigned short f2bf(float f) {
  unsigned u = __float_as_uint(f);
  u += 0x7FFFu + ((u >> 16) & 1u);          // round-to-nearest-even
  return (unsigned short)(u >> 16);
}
__device__ __forceinline__ float gelu(float v) {
  return 0.5f * v * (1.0f + erff(v * 0.70710678118f));
}
__device__ __forceinline__ floatx2 bfpair(unsigned u) {
  floatx2 r;
  r[0] = __uint_as_float(u << 16);
  r[1] = __uint_as_float(u & 0xffff0000u);
  return r;
}

__device__ __forceinline__ float enc_val(int node, int d) {
  float hp, vp;
  if (node == 0) { hp = -0.5f; vp = -1.0f; }
  else {
    int v = 31 - __clz(node);
    hp = (float)(node - (1 << v));
    vp = (float)v;
  }
  float pos = (d < 64) ? hp : vp;
  int i = ((d < 64) ? d : (d - 64)) >> 1;
  float inv = __expf(-(float)i * LOG1E4_OVER_32);
  float ang = pos * inv;
  return (d & 1) ? __cosf(ang) : __sinf(ang);
}

// Cache window for block jb at level cd — MUST be identical in the eoff
// precompute and in the gather staging (single shared definition).
__device__ __forceinline__ void win_cd(int jb, int cd, int& lo_, int& wd_) {
  int g0 = 1024 + jb * 32, g1 = g0 + 31;
  int a0 = g0 >> (10 - cd), a1 = g1 >> (10 - cd);
  int l = a0 - SLACK, h = a1 + SLACK;
  int lvlo = 1 << cd, lvhi = (2 << cd) - 1;
  lo_ = l < lvlo ? lvlo : l;
  int hh = h > lvhi ? lvhi : h;
  int w = hh - lo_ + 1;
  wd_ = w < 0 ? 0 : w;
}

// ---------------------------------------------------------------------------
// Per-group barrier over 32 blocks. Group g = bid & 7.
__device__ __forceinline__ void gbarN(int* bar, int slot) {
  __syncthreads();
  if (threadIdx.x == 0) {
    int g = blockIdx.x & 7;
    int* base = bar + (slot * 8 + g) * 64;
    __threadfence();                           // release (L2 wb)
    if (__hip_atomic_fetch_add(base, 1, __ATOMIC_RELAXED,
                               __HIP_MEMORY_SCOPE_AGENT) == 31)
      __hip_atomic_store(base + 32, 1, __ATOMIC_RELAXED,
                         __HIP_MEMORY_SCOPE_AGENT);
    while (!__hip_atomic_load(base + 32, __ATOMIC_RELAXED,
                              __HIP_MEMORY_SCOPE_AGENT))
      __builtin_amdgcn_s_sleep(1);
    __threadfence();                           // acquire (L2 inv)
  }
  __syncthreads();
}

// agg store helper: 4 dims (quad j) of node g
__device__ __forceinline__ void st_agg(unsigned short* ah, int b, int g, int j,
                                       floatx4 S, float inv) {
  ushort4 o;
  o.x = f2bf(S[0] * inv); o.y = f2bf(S[1] * inv);
  o.z = f2bf(S[2] * inv); o.w = f2bf(S[3] * inv);
  *(ushort4*)&ah[(size_t)(b * NN + g) * AHS + j * 4] = o;
}

// ---------------------------------------------------------------------------
// Tree build + layer-0 LN/GELU + in-LDS subtree sums. Pyramids run 2 levels
// per barrier-phase (intermediate level computed in-register, both written).
// Stashes x0 of the t32 tile rows into xci on WAVES 8-15. Writes x0 to global
// for leaf rows (k>=64) AND internal rows k<=32.
__device__ __forceinline__ void ph_tree(char* smemc, int b, int s,
                                        const float* __restrict__ elements,
                                        float* __restrict__ x,
                                        float* __restrict__ lvl4,
                                        unsigned short* __restrict__ ah,
                                        const float* __restrict__ gamma,
                                        const float* __restrict__ beta,
                                        float* __restrict__ sroot,
                                        float* xci, int* bar) {
  float* sm = (float*)smemc;                  // 127*128 floats = 63.5 KB
  floatx4* smv = (floatx4*)smemc;             // same memory, 32 vec4 per row
  int tid = threadIdx.x;
  const float4* src = (const float4*)(elements + (size_t)(b * LEAFN + s * 64) * DD);
  for (int i = tid; i < 2048; i += NT) {
    int f = i * 4;
    int j = f >> 7, d = f & 127;
    *(float4*)&sm[(63 + j) * DD + d] = src[i];
  }
  __syncthreads();
  // mean pyramid, fused level pairs {5,4},{3,2},{1,0} (bit-identical adds)
  {
    for (int idx = tid; idx < 16 * 32; idx += NT) {
      int k = 16 + (idx >> 5), j = idx & 31;
      floatx4 a = 0.5f * (smv[(4 * k - 1) * 32 + j] + smv[(4 * k) * 32 + j]);
      floatx4 c = 0.5f * (smv[(4 * k + 1) * 32 + j] + smv[(4 * k + 2) * 32 + j]);
      smv[(2 * k - 1) * 32 + j] = a;
      smv[(2 * k) * 32 + j] = c;
      smv[(k - 1) * 32 + j] = 0.5f * (a + c);
    }
    __syncthreads();
    for (int idx = tid; idx < 4 * 32; idx += NT) {
      int k = 4 + (idx >> 5), j = idx & 31;
      floatx4 a = 0.5f * (smv[(4 * k - 1) * 32 + j] + smv[(4 * k) * 32 + j]);
      floatx4 c = 0.5f * (smv[(4 * k + 1) * 32 + j] + smv[(4 * k + 2) * 32 + j]);
      smv[(2 * k - 1) * 32 + j] = a;
      smv[(2 * k) * 32 + j] = c;
      smv[(k - 1) * 32 + j] = 0.5f * (a + c);
    }
    __syncthreads();
    for (int idx = tid; idx < 32; idx += NT) {
      int j = idx;
      floatx4 a = 0.5f * (smv[3 * 32 + j] + smv[4 * 32 + j]);
      floatx4 c = 0.5f * (smv[5 * 32 + j] + smv[6 * 32 + j]);
      smv[1 * 32 + j] = a;
      smv[2 * 32 + j] = c;
      floatx4 r = 0.5f * (a + c);
      smv[j] = r;
      ((floatx4*)&lvl4[(size_t)(b * 16 + s) * DD])[j] = r;   // same thread, reg
    }
  }
  __syncthreads();
  if (tid == 0) {                             // release lvl4-ready flag
    __threadfence();
    __hip_atomic_store(bar + 1536 + b * 64 + s * 4, 1, __ATOMIC_RELAXED,
                       __HIP_MEMORY_SCOPE_AGENT);
  }
  // x = feat + enc; paired sin/cos (d fixed per thread: NT % 128 == 0).
  {
    int d2 = tid & 63;                        // pair index, loop-invariant
    int i = d2 & 31;
    float inv = __expf(-(float)i * LOG1E4_OVER_32);
    bool lowhalf = d2 < 32;                   // d<64 -> horizontal pos
    for (int idx2 = tid; idx2 < 127 * 64; idx2 += NT) {
      int row = idx2 >> 6;
      int k = row + 1;
      int lv = 31 - __clz(k);
      int g = ((16 + s) << lv) | (k - (1 << lv));
      float vp = (float)(lv + 4);
      float hp = (float)(g - (16 << lv));
      float pos = lowhalf ? hp : vp;
      float sv, cv;
      __sincosf(pos * inv, &sv, &cv);
      int base = row * DD + 2 * d2;
      float xv0 = sm[base] + sv;
      float xv1 = sm[base + 1] + cv;
      sm[base] = xv0; sm[base + 1] = xv1;
      if (k >= 64 || k <= 32) {
        float2 o = make_float2(xv0, xv1);
        *(float2*)&x[((size_t)(b * NN + g)) * DD + 2 * d2] = o;
      }
    }
  }
  __syncthreads();
  // stash x0 for this block's t32 gemm tile (waves 8-15 run it later)
  {
    int wave = tid >> 6, lane = tid & 63;
    if (wave >= 8) {
      int wl = wave & 7;
      int mt = wl >> 2, nq = wl & 3;
      int m = lane & 15, q = lane >> 4;
#pragma unroll
      for (int ci = 0; ci < 2; ++ci)
#pragma unroll
        for (int r = 0; r < 4; ++r) {
          int t = 32 + mt * 16 + q * 4 + r;
          int k = (t == 63) ? 1 : t + 1;
          int d = (nq * 2 + ci) * 16 + m;
          xci[ci * 4 + r] = sm[(k - 1) * DD + d];
        }
    }
  }
  __syncthreads();
  // LN + GELU: h -> ah(+128) AND h overwrites sm (fp32). float4 LDS access.
  {
    int sub = tid & 7, dp = sub * 16;
    for (int rr = tid >> 3; rr < 127; rr += NT / 8) {
      float* rowp = &sm[rr * DD + dp];
      float4 q0 = *(float4*)rowp;
      float4 q1 = *(float4*)(rowp + 4);
      float4 q2 = *(float4*)(rowp + 8);
      float4 q3 = *(float4*)(rowp + 12);
      float v[16] = {q0.x, q0.y, q0.z, q0.w, q1.x, q1.y, q1.z, q1.w,
                     q2.x, q2.y, q2.z, q2.w, q3.x, q3.y, q3.z, q3.w};
      float s1 = 0.f, s2 = 0.f;
#pragma unroll
      for (int j = 0; j < 16; ++j) { s1 += v[j]; s2 += v[j] * v[j]; }
      s1 += __shfl_xor(s1, 1); s2 += __shfl_xor(s2, 1);
      s1 += __shfl_xor(s1, 2); s2 += __shfl_xor(s2, 2);
      s1 += __shfl_xor(s1, 4); s2 += __shfl_xor(s2, 4);
      float mu = s1 * (1.0f / 128.0f);
      float var = s2 * (1.0f / 128.0f) - mu * mu;
      float rinv = rsqrtf(var + 1e-5f);
      int k = rr + 1, lv = 31 - __clz(k);
      int g = ((16 + s) << lv) | (k - (1 << lv));
      __attribute__((aligned(16))) unsigned short o[16];
      float hv[16];
#pragma unroll
      for (int j = 0; j < 16; ++j) {
        hv[j] = gelu((v[j] - mu) * rinv * gamma[dp + j] + beta[dp + j]);
        o[j] = f2bf(hv[j]);
      }
      *(float4*)rowp        = make_float4(hv[0], hv[1], hv[2], hv[3]);
      *(float4*)(rowp + 4)  = make_float4(hv[4], hv[5], hv[6], hv[7]);
      *(float4*)(rowp + 8)  = make_float4(hv[8], hv[9], hv[10], hv[11]);
      *(float4*)(rowp + 12) = make_float4(hv[12], hv[13], hv[14], hv[15]);
      unsigned short* dst = &ah[(size_t)(b * NN + g) * AHS + 128 + dp];
      *(uint4*)&dst[0] = *(uint4*)&o[0];
      *(uint4*)&dst[8] = *(uint4*)&o[8];
    }
  }
  __syncthreads();
  // subtree-sum pyramid, fused pairs {5,4},{3,2},{1,0}; agg -> ah(+0).
  // Convention: S(node n) stored at slot (2n-1). inv(lv)=1/(2^(7-lv)-2).
  {
    for (int idx = tid; idx < 16 * 32; idx += NT) {
      int k = 16 + (idx >> 5), j = idx & 31;
      floatx4 sa = smv[(4 * k - 1) * 32 + j] + smv[(4 * k) * 32 + j];
      floatx4 sc = smv[(4 * k + 1) * 32 + j] + smv[(4 * k + 2) * 32 + j];
      floatx4 sk = (smv[(2 * k - 1) * 32 + j] + smv[(2 * k) * 32 + j]) + (sa + sc);
      smv[(4 * k - 1) * 32 + j] = sa;
      smv[(4 * k + 1) * 32 + j] = sc;
      smv[(2 * k - 1) * 32 + j] = sk;
      st_agg(ah, b, ((16 + s) << 5) | (2 * k - 32), j, sa, 0.5f);
      st_agg(ah, b, ((16 + s) << 5) | (2 * k + 1 - 32), j, sc, 0.5f);
      st_agg(ah, b, ((16 + s) << 4) | (k - 16), j, sk, 1.0f / 6.0f);
    }
    __syncthreads();
    for (int idx = tid; idx < 4 * 32; idx += NT) {
      int k = 4 + (idx >> 5), j = idx & 31;
      floatx4 sa = (smv[(4 * k - 1) * 32 + j] + smv[(4 * k) * 32 + j]) +
                   (smv[(8 * k - 1) * 32 + j] + smv[(8 * k + 1) * 32 + j]);
      floatx4 sc = (smv[(4 * k + 1) * 32 + j] + smv[(4 * k + 2) * 32 + j]) +
                   (smv[(8 * k + 3) * 32 + j] + smv[(8 * k + 5) * 32 + j]);
      floatx4 sk = (smv[(2 * k - 1) * 32 + j] + smv[(2 * k) * 32 + j]) + (sa + sc);
      smv[(4 * k - 1) * 32 + j] = sa;
      smv[(4 * k + 1) * 32 + j] = sc;
      smv[(2 * k - 1) * 32 + j] = sk;
      st_agg(ah, b, ((16 + s) << 3) | (2 * k - 8), j, sa, 1.0f / 14.0f);
      st_agg(ah, b, ((16 + s) << 3) | (2 * k + 1 - 8), j, sc, 1.0f / 14.0f);
      st_agg(ah, b, ((16 + s) << 2) | (k - 4), j, sk, 1.0f / 30.0f);
    }
    __syncthreads();
    for (int idx = tid; idx < 32; idx += NT) {
      int j = idx;
      floatx4 sa = (smv[3 * 32 + j] + smv[4 * 32 + j]) +
                   (smv[7 * 32 + j] + smv[9 * 32 + j]);
      floatx4 sc = (smv[5 * 32 + j] + smv[6 * 32 + j]) +
                   (smv[11 * 32 + j] + smv[13 * 32 + j]);
      floatx4 sk = (smv[1 * 32 + j] + smv[2 * 32 + j]) + (sa + sc);
      st_agg(ah, b, ((16 + s) << 1) | 0, j, sa, 1.0f / 62.0f);
      st_agg(ah, b, ((16 + s) << 1) | 1, j, sc, 1.0f / 62.0f);
      st_agg(ah, b, (16 + s), j, sk, 1.0f / 126.0f);
      ((floatx4*)&sroot[(size_t)(b * 16 + s) * DD])[j] = sk;
    }
  }
  // gbar0's syncthreads covers the tail; final phase LDS use (<8KB) is
  // disjoint from the msk/fb zero at 58240+ done by the caller.
}

// ---------------------------------------------------------------------------
// Top nodes 0..15: x0 into LDS xs, layer-0 h -> ah.
__device__ __forceinline__ void ph_top(char* smemc, int b,
                                       const float* __restrict__ lvl4,
                                       unsigned short* __restrict__ ah,
                                       const float* __restrict__ gamma,
                                       const float* __restrict__ beta) {
  float (*xs)[DD] = (float(*)[DD])smemc;      // 8 KB
  int tid = threadIdx.x;
  if (tid < 128) {
    int d = tid;
    float v[16];
    for (int j = 0; j < 16; ++j) v[j] = lvl4[(b * 16 + j) * DD + d];
    for (int j = 0; j < 8; ++j) v[j] = 0.5f * (v[2 * j] + v[2 * j + 1]);
    for (int j = 0; j < 8; ++j) xs[8 + j][d] = v[j] + enc_val(8 + j, d);
    for (int j = 0; j < 4; ++j) v[j] = 0.5f * (v[2 * j] + v[2 * j + 1]);
    for (int j = 0; j < 4; ++j) xs[4 + j][d] = v[j] + enc_val(4 + j, d);
    for (int j = 0; j < 2; ++j) v[j] = 0.5f * (v[2 * j] + v[2 * j + 1]);
    for (int j = 0; j < 2; ++j) xs[2 + j][d] = v[j] + enc_val(2 + j, d);
    v[0] = 0.5f * (v[0] + v[1]);
    xs[1][d] = v[0] + enc_val(1, d);
    xs[0][d] = -1.0f + enc_val(0, d);
  }
  __syncthreads();
  if (tid < 128) {
    int rr = tid >> 3, sub = tid & 7, dp = sub * 16;
    float w[16], s1 = 0.f, s2 = 0.f;
#pragma unroll
    for (int j = 0; j < 16; ++j) { w[j] = xs[rr][dp + j]; s1 += w[j]; s2 += w[j] * w[j]; }
    s1 += __shfl_xor(s1, 1); s2 += __shfl_xor(s2, 1);
    s1 += __shfl_xor(s1, 2); s2 += __shfl_xor(s2, 2);
    s1 += __shfl_xor(s1, 4); s2 += __shfl_xor(s2, 4);
    float mu = s1 * (1.0f / 128.0f);
    float var = s2 * (1.0f / 128.0f) - mu * mu;
    float rinv = rsqrtf(var + 1e-5f);
    __attribute__((aligned(16))) unsigned short o[16];
#pragma unroll
    for (int j = 0; j < 16; ++j)
      o[j] = f2bf(gelu((w[j] - mu) * rinv * gamma[dp + j] + beta[dp + j]));
    unsigned short* dst = &ah[(size_t)(b * NN + rr) * AHS + 128 + dp];
    *(uint4*)&dst[0] = *(uint4*)&o[0];
    *(uint4*)&dst[8] = *(uint4*)&o[8];
  }
  __syncthreads();
}

// ---------------------------------------------------------------------------
// Subtree sums for L1: reads h' from ah(+256), agg -> ah(+0), sroot.
// Fused level pairs {4,3},{2,1},{0}: 3 internal barriers.
__device__ __forceinline__ void ph_aggsub(char* smemc, int b, int s,
                                          unsigned short* ah,
                                          float* __restrict__ sroot) {
  floatx4 (*S)[32] = (floatx4(*)[32])smemc;   // 32 KB
  int tid = threadIdx.x;
  for (int idx = tid; idx < 32 * 32; idx += NT) {
    int k = 32 + (idx >> 5), q = idx & 31;
    int c = (16 + s) * 64 + (2 * k - 64);
    size_t a0 = (size_t)(b * NN + c) * AHS + 256 + q * 4;
    ushort4 u0 = *(const ushort4*)&ah[a0];
    ushort4 u1 = *(const ushort4*)&ah[a0 + AHS];
    floatx4 v;
    v[0] = bf2f(u0.x) + bf2f(u1.x);
    v[1] = bf2f(u0.y) + bf2f(u1.y);
    v[2] = bf2f(u0.z) + bf2f(u1.z);
    v[3] = bf2f(u0.w) + bf2f(u1.w);
    S[k][q] = v;
    st_agg(ah, b, (16 + s) * 32 + (k - 32), q, v, 0.5f);
  }
  __syncthreads();
  // {4,3}: per lv3 node k=8..15
  for (int idx = tid; idx < 8 * 32; idx += NT) {
    int k = 8 + (idx >> 5), q = idx & 31;
    size_t aa = (size_t)(b * NN + (((16 + s) << 5) | (4 * k - 32))) * AHS + 256 + q * 4;
    ushort4 u0 = *(const ushort4*)&ah[aa];
    ushort4 u1 = *(const ushort4*)&ah[aa + AHS];
    size_t ab = (size_t)(b * NN + (((16 + s) << 5) | (4 * k + 2 - 32))) * AHS + 256 + q * 4;
    ushort4 w0 = *(const ushort4*)&ah[ab];
    ushort4 w1 = *(const ushort4*)&ah[ab + AHS];
    size_t ac = (size_t)(b * NN + (((16 + s) << 4) | (2 * k - 16))) * AHS + 256 + q * 4;
    ushort4 h0 = *(const ushort4*)&ah[ac];
    ushort4 h1 = *(const ushort4*)&ah[ac + AHS];
    floatx4 s4a, s4b, s3;
    floatx4 sc0 = S[4 * k][q], sc1 = S[4 * k + 1][q];
    floatx4 sd0 = S[4 * k + 2][q], sd1 = S[4 * k + 3][q];
    s4a[0] = bf2f(u0.x) + bf2f(u1.x) + sc0[0] + sc1[0];
    s4a[1] = bf2f(u0.y) + bf2f(u1.y) + sc0[1] + sc1[1];
    s4a[2] = bf2f(u0.z) + bf2f(u1.z) + sc0[2] + sc1[2];
    s4a[3] = bf2f(u0.w) + bf2f(u1.w) + sc0[3] + sc1[3];
    s4b[0] = bf2f(w0.x) + bf2f(w1.x) + sd0[0] + sd1[0];
    s4b[1] = bf2f(w0.y) + bf2f(w1.y) + sd0[1] + sd1[1];
    s4b[2] = bf2f(w0.z) + bf2f(w1.z) + sd0[2] + sd1[2];
    s4b[3] = bf2f(w0.w) + bf2f(w1.w) + sd0[3] + sd1[3];
    s3[0] = bf2f(h0.x) + bf2f(h1.x) + s4a[0] + s4b[0];
    s3[1] = bf2f(h0.y) + bf2f(h1.y) + s4a[1] + s4b[1];
    s3[2] = bf2f(h0.z) + bf2f(h1.z) + s4a[2] + s4b[2];
    s3[3] = bf2f(h0.w) + bf2f(h1.w) + s4a[3] + s4b[3];
    S[2 * k][q] = s4a; S[2 * k + 1][q] = s4b; S[k][q] = s3;
    st_agg(ah, b, ((16 + s) << 4) | (2 * k - 16), q, s4a, 1.0f / 6.0f);
    st_agg(ah, b, ((16 + s) << 4) | (2 * k + 1 - 16), q, s4b, 1.0f / 6.0f);
    st_agg(ah, b, ((16 + s) << 3) | (k - 8), q, s3, 1.0f / 14.0f);
  }
  __syncthreads();
  // {2,1}: per lv1 node k=2..3
  for (int idx = tid; idx < 2 * 32; idx += NT) {
    int k = 2 + (idx >> 5), q = idx & 31;
    size_t aa = (size_t)(b * NN + (((16 + s) << 3) | (4 * k - 8))) * AHS + 256 + q * 4;
    ushort4 u0 = *(const ushort4*)&ah[aa];
    ushort4 u1 = *(const ushort4*)&ah[aa + AHS];
    size_t ab = (size_t)(b * NN + (((16 + s) << 3) | (4 * k + 2 - 8))) * AHS + 256 + q * 4;
    ushort4 w0 = *(const ushort4*)&ah[ab];
    ushort4 w1 = *(const ushort4*)&ah[ab + AHS];
    size_t ac = (size_t)(b * NN + (((16 + s) << 2) | (2 * k - 4))) * AHS + 256 + q * 4;
    ushort4 h0 = *(const ushort4*)&ah[ac];
    ushort4 h1 = *(const ushort4*)&ah[ac + AHS];
    floatx4 s2a, s2b, s1v;
    floatx4 sc0 = S[4 * k][q], sc1 = S[4 * k + 1][q];
    floatx4 sd0 = S[4 * k + 2][q], sd1 = S[4 * k + 3][q];
    s2a[0] = bf2f(u0.x) + bf2f(u1.x) + sc0[0] + sc1[0];
    s2a[1] = bf2f(u0.y) + bf2f(u1.y) + sc0[1] + sc1[1];
    s2a[2] = bf2f(u0.z) + bf2f(u1.z) + sc0[2] + sc1[2];
    s2a[3] = bf2f(u0.w) + bf2f(u1.w) + sc0[3] + sc1[3];
    s2b[0] = bf2f(w0.x) + bf2f(w1.x) + sd0[0] + sd1[0];
    s2b[1] = bf2f(w0.y) + bf2f(w1.y) + sd0[1] + sd1[1];
    s2b[2] = bf2f(w0.z) + bf2f(w1.z) + sd0[2] + sd1[2];
    s2b[3] = bf2f(w0.w) + bf2f(w1.w) + sd0[3] + sd1[3];
    s1v[0] = bf2f(h0.x) + bf2f(h1.x) + s2a[0] + s2b[0];
    s1v[1] = bf2f(h0.y) + bf2f(h1.y) + s2a[1] + s2b[1];
    s1v[2] = bf2f(h0.z) + bf2f(h1.z) + s2a[2] + s2b[2];
    s1v[3] = bf2f(h0.w) + bf2f(h1.w) + s2a[3] + s2b[3];
    S[2 * k][q] = s2a; S[2 * k + 1][q] = s2b; S[k][q] = s1v;
    st_agg(ah, b, ((16 + s) << 2) | (2 * k - 4), q, s2a, 1.0f / 30.0f);
    st_agg(ah, b, ((16 + s) << 2) | (2 * k + 1 - 4), q, s2b, 1.0f / 30.0f);
    st_agg(ah, b, ((16 + s) << 1) | (k - 2), q, s1v, 1.0f / 62.0f);
  }
  __syncthreads();
  // {0}: root of subtree; sroot written directly from registers
  for (int idx = tid; idx < 32; idx += NT) {
    int q = idx;
    size_t aa = (size_t)(b * NN + (((16 + s) << 1) | 0)) * AHS + 256 + q * 4;
    ushort4 u0 = *(const ushort4*)&ah[aa];
    ushort4 u1 = *(const ushort4*)&ah[aa + AHS];
    floatx4 sc0 = S[2][q], sc1 = S[3][q];
    floatx4 s0v;
    s0v[0] = bf2f(u0.x) + bf2f(u1.x) + sc0[0] + sc1[0];
    s0v[1] = bf2f(u0.y) + bf2f(u1.y) + sc0[1] + sc1[1];
    s0v[2] = bf2f(u0.z) + bf2f(u1.z) + sc0[2] + sc1[2];
    s0v[3] = bf2f(u0.w) + bf2f(u1.w) + sc0[3] + sc1[3];
    st_agg(ah, b, (16 + s), q, s0v, 1.0f / 126.0f);
    ((floatx4*)sroot)[(size_t)(b * 16 + s) * 32 + q] = s0v;
  }
}

// ---------------------------------------------------------------------------
// MFMA leaf gather, single-pass, 2 internal barriers. Stage + tail-zero are
// merged in one phase (disjoint SB addresses; staged rows fully overwritten;
// tile pads never read by the B-fetch). msk/fb zeroed in P0 (pre-gbar0);
// invdeg set here on build (P1), read 2 barriers later. msk/invdeg/fb persist
// P1->P2 (P1 aggl writes only touch staged-row tiles: bytes < 8704 < 41600).
__device__ __forceinline__ void ph_leafagg(char* smemc, int b, int jb,
                                           const int* __restrict__ srcv,
                                           const int* __restrict__ dstv,
                                           const int* __restrict__ s0a,
                                           const int* __restrict__ s1a,
                                           const unsigned short* __restrict__ eoff,
                                           unsigned short* ah, int hoff,
                                           int build) {
  int tid = threadIdx.x;
  int lane = tid & 63, wv = tid >> 6;
  unsigned short* SB = (unsigned short*)(smemc + SB_OFF);
  unsigned* msk = (unsigned*)(smemc + MSK_OFF);
  float* invdeg = (float*)(smemc + DEG_OFF);
  unsigned int* fb = (unsigned int*)(smemc + FB_OFF);
  unsigned short* aggl = (unsigned short*)(smemc + AGGL_OFF);
  int rbase = b * NN + 1024 + jb * 32;

  int lo[11], wd[11], off[11];
  int acc_off = 0;
#pragma unroll
  for (int cd = 10; cd >= 1; --cd) {
    win_cd(jb, cd, lo[cd], wd[cd]);
    off[cd] = acc_off;
    acc_off += wd[cd];
  }

  // phase 1: [build] msk edge-scatter + invdeg; stage H rows into SB frag
  // layout; zero the tail rows kr in [acc_off, 224). All disjoint addresses.
  if (build) {
    int E0 = s0a[rbase], E1 = s1a[rbase + 31];
    for (int e = E0 + tid; e < E1; e += NT) {
      int leaf = dstv[e] - rbase;
      unsigned kr = eoff[e];
      if (kr == 0xFFFFu) atomicOr(fb, 1u << leaf);
      else atomicOr(&msk[leaf * 8 + (kr >> 5)], 1u << (kr & 31));
    }
    if (tid < 32)
      invdeg[tid] = 1.0f / (float)max(s1a[rbase + tid] - s0a[rbase + tid], 1);
  }
#pragma unroll
  for (int cd = 10; cd >= 1; --cd) {
    int w = wd[cd];
    for (int t = tid; t < w * 16; t += NT) {
      int row = t >> 4, seg = t & 15;
      int kr = off[cd] + row;
      uint4 u = *(const uint4*)&ah[(size_t)(b * NN + lo[cd] + row) * AHS + hoff + seg * 8];
      unsigned short* p = SB + ((kr >> 5) * 8 + (seg >> 1)) * SBT +
                          ((kr & 31) >> 3) * 128 + (seg & 1) * 64 + (kr & 7);
      p[0]  = (unsigned short)(u.x & 0xffff);
      p[8]  = (unsigned short)(u.x >> 16);
      p[16] = (unsigned short)(u.y & 0xffff);
      p[24] = (unsigned short)(u.y >> 16);
      p[32] = (unsigned short)(u.z & 0xffff);
      p[40] = (unsigned short)(u.z >> 16);
      p[48] = (unsigned short)(u.w & 0xffff);
      p[56] = (unsigned short)(u.w >> 16);
    }
  }
  {
    int ntail = (224 - acc_off) * 16;
    for (int t = tid; t < ntail; t += NT) {
      int kr = acc_off + (t >> 4), seg = t & 15;
      unsigned short* p = SB + ((kr >> 5) * 8 + (seg >> 1)) * SBT +
                          ((kr & 31) >> 3) * 128 + (seg & 1) * 64 + (kr & 7);
      p[0] = 0; p[8] = 0; p[16] = 0; p[24] = 0;
      p[32] = 0; p[40] = 0; p[48] = 0; p[56] = 0;
    }
  }
  __syncthreads();                                             // B1

  // MFMA: 7 K-chunks, A built from bitmask in registers
  int m = lane & 15, q = lane >> 4;
  int mt = wv >> 3, nt = wv & 7;
  int arow = mt * 16 + m;
  floatx4 acc = (floatx4){0.f, 0.f, 0.f, 0.f};
#pragma unroll
  for (int kcl = 0; kcl < 7; ++kcl) {
    unsigned mw = msk[arow * 8 + kcl];
    unsigned bits = (mw >> (q * 8)) & 0xffu;
    union { uint4 u; bf16x8 v; } A;
    A.u.x = ((bits & 1u)  ? 0x3F80u : 0u) | ((bits & 2u)   ? 0x3F800000u : 0u);
    A.u.y = ((bits & 4u)  ? 0x3F80u : 0u) | ((bits & 8u)   ? 0x3F800000u : 0u);
    A.u.z = ((bits & 16u) ? 0x3F80u : 0u) | ((bits & 32u)  ? 0x3F800000u : 0u);
    A.u.w = ((bits & 64u) ? 0x3F80u : 0u) | ((bits & 128u) ? 0x3F800000u : 0u);
    bf16x8 bb = *(const bf16x8*)&SB[(kcl * 8 + nt) * SBT + lane * 8];
    acc = __builtin_amdgcn_mfma_f32_16x16x32_bf16(A.v, bb, acc, 0, 0, 0);
  }
  __syncthreads();                                             // B2 (SB dead)

  unsigned fbm = *fb;
#pragma unroll
  for (int r = 0; r < 4; ++r) {
    int leaf = mt * 16 + q * 4 + r;
    if (!((fbm >> leaf) & 1u))
      aggl[leaf * CSTRIDE + nt * 16 + m] = f2bf(acc[r] * invdeg[leaf]);
  }
  // safety net: out-of-window edges (never expected) -> scalar full redo
  if (fbm && tid < 512) {
    int leaf = tid >> 4, c = tid & 15;
    if ((fbm >> leaf) & 1u) {
      int e0 = s0a[rbase + leaf], e1 = s1a[rbase + leaf];
      floatx2 a0 = {0.f, 0.f}, a1 = {0.f, 0.f}, a2 = {0.f, 0.f}, a3 = {0.f, 0.f};
      for (int e = e0; e < e1; ++e) {
        int g = srcv[e] - b * NN;
        uint4 u = *(const uint4*)&ah[(size_t)(b * NN + g) * AHS + hoff + c * 8];
        a0 += bfpair(u.x); a1 += bfpair(u.y); a2 += bfpair(u.z); a3 += bfpair(u.w);
      }
      float inv = 1.0f / (float)max(e1 - e0, 1);
      __attribute__((aligned(16))) unsigned short o[8];
      o[0] = f2bf(a0[0] * inv); o[1] = f2bf(a0[1] * inv);
      o[2] = f2bf(a1[0] * inv); o[3] = f2bf(a1[1] * inv);
      o[4] = f2bf(a2[0] * inv); o[5] = f2bf(a2[1] * inv);
      o[6] = f2bf(a3[0] * inv); o[7] = f2bf(a3[1] * inv);
      *(uint4*)&aggl[leaf * CSTRIDE + c * 8] = *(uint4*)&o[0];
    }
  }
}

// ---------------------------------------------------------------------------
// Finish agg for nodes 0..15 (tid<128); h at +hoff, closed-form deg.
__device__ __forceinline__ void ph_topfin(int b,
                                          const float* __restrict__ sroot,
                                          unsigned short* ah, int hoff) {
  int d = threadIdx.x;
  float S16[16], h16[16], Sv[16];
#pragma unroll
  for (int j = 0; j < 16; ++j) S16[j] = sroot[(size_t)(b * 16 + j) * DD + d];
#pragma unroll
  for (int j = 0; j < 16; ++j)
    h16[j] = bf2f(ah[(size_t)(b * NN + 16 + j) * AHS + hoff + d]);
#pragma unroll
  for (int k = 8; k < 16; ++k)
    Sv[k] = h16[2 * k - 16] + h16[2 * k - 15] + S16[2 * k - 16] + S16[2 * k - 15];
#pragma unroll
  for (int k = 7; k >= 1; --k)
    Sv[k] = bf2f(ah[(size_t)(b * NN + 2 * k) * AHS + hoff + d]) +
            bf2f(ah[(size_t)(b * NN + 2 * k + 1) * AHS + hoff + d]) +
            Sv[2 * k] + Sv[2 * k + 1];
#pragma unroll
  for (int k = 1; k < 16; ++k) {
    int dv = 31 - __clz(k);
    float inv = 1.0f / (float)((1 << (11 - dv)) - 2);
    ah[(size_t)(b * NN + k) * AHS + d] = f2bf(Sv[k] * inv);
  }
  ah[(size_t)(b * NN) * AHS + d] = f2bf(0.0f);
}

// ---------------------------------------------------------------------------
// 32-row leaf GEMM tile (contiguous rows at rowbase). agg A-operand (kc<4)
// from the aggl LDS buffer. Runs on waves 0-7 (concurrently with ph_gemm32s
// on waves 8-15); exactly 2 __syncthreads when first_layer, else 0.
__device__ __forceinline__ void ph_gemm32(char* redc, const unsigned short* aggl,
                                          int rowbase, unsigned short* ah,
                                          const unsigned short* __restrict__ wfl,
                                          const float* __restrict__ bn,
                                          float* __restrict__ x, int hoff_in,
                                          const float* __restrict__ gamma,
                                          const float* __restrict__ beta,
                                          float* xc, int first_layer) {
  int wave = threadIdx.x >> 6, lane = threadIdx.x & 63;
  bool act = wave < 8;
  int wl = wave & 7;
  int mt = wl >> 2, nq = wl & 3;
  int r0 = rowbase + mt * 16;
  int m = lane & 15, q = lane >> 4;
  floatx4 acc[2];
  acc[0] = (floatx4){0.f, 0.f, 0.f, 0.f};
  acc[1] = (floatx4){0.f, 0.f, 0.f, 0.f};
  if (act) {
    const unsigned short* arow = ah + (size_t)(r0 + m) * AHS + q * 8;
    const bf16x8* B = (const bf16x8*)wfl + lane;
#pragma unroll
    for (int kc = 0; kc < 8; ++kc) {
      bf16x8 a0;
      if (kc < 4)
        a0 = *(const bf16x8*)&aggl[(mt * 16 + m) * CSTRIDE + kc * 32 + q * 8];
      else
        a0 = *(const bf16x8*)(arow + hoff_in + (kc - 4) * 32);
#pragma unroll
      for (int ci = 0; ci < 2; ++ci) {
        bf16x8 bb = B[(kc * 8 + nq * 2 + ci) * 64];
        acc[ci] = __builtin_amdgcn_mfma_f32_16x16x32_bf16(a0, bb, acc[ci], 0, 0, 0);
      }
    }
  }
  if (first_layer) {
    float s1[4] = {0.f, 0.f, 0.f, 0.f}, s2[4] = {0.f, 0.f, 0.f, 0.f};
    if (act) {
#pragma unroll
      for (int ci = 0; ci < 2; ++ci) {
        int col = (nq * 2 + ci) * 16 + m;
        float bias = bn[col];
#pragma unroll
        for (int r = 0; r < 4; ++r) {
          int row = r0 + q * 4 + r;
          float v = x[(size_t)row * DD + col] + acc[ci][r] + bias;
          xc[ci * 4 + r] = v;
          s1[r] += v; s2[r] += v * v;
        }
      }
#pragma unroll
      for (int r = 0; r < 4; ++r) {
        s1[r] += __shfl_xor(s1[r], 1); s2[r] += __shfl_xor(s2[r], 1);
        s1[r] += __shfl_xor(s1[r], 2); s2[r] += __shfl_xor(s2[r], 2);
        s1[r] += __shfl_xor(s1[r], 4); s2[r] += __shfl_xor(s2[r], 4);
        s1[r] += __shfl_xor(s1[r], 8); s2[r] += __shfl_xor(s2[r], 8);
      }
    }
    float* red = (float*)redc;
    int rl = mt * 16 + q * 4;
    __syncthreads();
    if (act && m == 0) {
#pragma unroll
      for (int r = 0; r < 4; ++r) {
        red[(rl + r) * 4 + nq] = s1[r];
        red[128 + (rl + r) * 4 + nq] = s2[r];
      }
    }
    __syncthreads();
    if (act) {
      float mu[4], rv[4];
#pragma unroll
      for (int r = 0; r < 4; ++r) {
        float t1 = red[(rl + r) * 4] + red[(rl + r) * 4 + 1] +
                   red[(rl + r) * 4 + 2] + red[(rl + r) * 4 + 3];
        float t2 = red[128 + (rl + r) * 4] + red[128 + (rl + r) * 4 + 1] +
                   red[128 + (rl + r) * 4 + 2] + red[128 + (rl + r) * 4 + 3];
        mu[r] = t1 * (1.0f / 128.0f);
        float var = t2 * (1.0f / 128.0f) - mu[r] * mu[r];
        rv[r] = rsqrtf(var + 1e-5f);
      }
#pragma unroll
      for (int ci = 0; ci < 2; ++ci) {
        int col = (nq * 2 + ci) * 16 + m;
        float gm = gamma[col], bt = beta[col];
#pragma unroll
        for (int r = 0; r < 4; ++r) {
          int row = r0 + q * 4 + r;
          float hh = gelu((xc[ci * 4 + r] - mu[r]) * rv[r] * gm + bt);
          ah[(size_t)row * AHS + 256 + col] = f2bf(hh);
        }
      }
    }
  } else {
    if (act) {
#pragma unroll
      for (int ci = 0; ci < 2; ++ci) {
        int col = (nq * 2 + ci) * 16 + m;
        float bias = bn[col];
#pragma unroll
        for (int r = 0; r < 4; ++r) {
          int row = r0 + q * 4 + r;
          x[(size_t)row * DD + col] = xc[ci * 4 + r] + acc[ci][r] + bias;
        }
      }
    }
  }
}

// ---------------------------------------------------------------------------
// 32-row internal GEMM tile with SCATTERED rows. Runs on waves 8-15.
// first_layer residual: from gx (global x0) when gx != nullptr, else xc.
// Exactly 2 __syncthreads when first_layer, else 0 (matches ph_gemm32).
__device__ __forceinline__ void ph_gemm32s(char* redc, int b, int sb, int tbase,
                                           unsigned short* ah,
                                           const unsigned short* __restrict__ wfl,
                                           const float* __restrict__ bn,
                                           float* __restrict__ x, int hoff_in,
                                           const float* __restrict__ gamma,
                                           const float* __restrict__ beta,
                                           float* xc, int first_layer,
                                           const float* __restrict__ gx) {
  int wave = threadIdx.x >> 6, lane = threadIdx.x & 63;
  bool act = wave >= 8;
  int wl = wave & 7;
  int mt = wl >> 2, nq = wl & 3;
  int m = lane & 15, q = lane >> 4;
  int tA = tbase + mt * 16 + m;
  int kA = (tA == 63) ? 1 : tA + 1;
  int lvA = 31 - __clz(kA);
  int rowA = b * NN + (((16 + sb) << lvA) | (kA - (1 << lvA)));
  int rowO[4];
#pragma unroll
  for (int r = 0; r < 4; ++r) {
    int t = tbase + mt * 16 + q * 4 + r;
    int k = (t == 63) ? 1 : t + 1;
    int lv = 31 - __clz(k);
    rowO[r] = b * NN + (((16 + sb) << lv) | (k - (1 << lv)));
  }
  floatx4 acc[2];
  acc[0] = (floatx4){0.f, 0.f, 0.f, 0.f};
  acc[1] = (floatx4){0.f, 0.f, 0.f, 0.f};
  if (act) {
    const unsigned short* arow = ah + (size_t)rowA * AHS + q * 8;
    const bf16x8* B = (const bf16x8*)wfl + lane;
#pragma unroll
    for (int kc = 0; kc < 8; ++kc) {
      int koff = (kc < 4) ? kc * 32 : hoff_in + (kc - 4) * 32;
      bf16x8 a0 = *(const bf16x8*)(arow + koff);
#pragma unroll
      for (int ci = 0; ci < 2; ++ci) {
        bf16x8 bb = B[(kc * 8 + nq * 2 + ci) * 64];
        acc[ci] = __builtin_amdgcn_mfma_f32_16x16x32_bf16(a0, bb, acc[ci], 0, 0, 0);
      }
    }
  }
  if (first_layer) {
    float s1[4] = {0.f, 0.f, 0.f, 0.f}, s2[4] = {0.f, 0.f, 0.f, 0.f};
    if (act) {
#pragma unroll
      for (int ci = 0; ci < 2; ++ci) {
        int col = (nq * 2 + ci) * 16 + m;
        float bias = bn[col];
#pragma unroll
        for (int r = 0; r < 4; ++r) {
          float x0 = gx ? gx[(size_t)rowO[r] * DD + col] : xc[ci * 4 + r];
          float v = x0 + acc[ci][r] + bias;
          xc[ci * 4 + r] = v;
          s1[r] += v; s2[r] += v * v;
        }
      }
#pragma unroll
      for (int r = 0; r < 4; ++r) {
        s1[r] += __shfl_xor(s1[r], 1); s2[r] += __shfl_xor(s2[r], 1);
        s1[r] += __shfl_xor(s1[r], 2); s2[r] += __shfl_xor(s2[r], 2);
        s1[r] += __shfl_xor(s1[r], 4); s2[r] += __shfl_xor(s2[r], 4);
        s1[r] += __shfl_xor(s1[r], 8); s2[r] += __shfl_xor(s2[r], 8);
      }
    }
    float* red = (float*)redc;
    int rl = mt * 16 + q * 4;
    __syncthreads();
    if (act && m == 0) {
#pragma unroll
      for (int r = 0; r < 4; ++r) {
        red[(rl + r) * 4 + nq] = s1[r];
        red[128 + (rl + r) * 4 + nq] = s2[r];
      }
    }
    __syncthreads();
    if (act) {
      float mu[4], rv[4];
#pragma unroll
      for (int r = 0; r < 4; ++r) {
        float t1 = red[(rl + r) * 4] + red[(rl + r) * 4 + 1] +
                   red[(rl + r) * 4 + 2] + red[(rl + r) * 4 + 3];
        float t2 = red[128 + (rl + r) * 4] + red[128 + (rl + r) * 4 + 1] +
                   red[128 + (rl + r) * 4 + 2] + red[128 + (rl + r) * 4 + 3];
        mu[r] = t1 * (1.0f / 128.0f);
        float var = t2 * (1.0f / 128.0f) - mu[r] * mu[r];
        rv[r] = rsqrtf(var + 1e-5f);
      }
#pragma unroll
      for (int ci = 0; ci < 2; ++ci) {
        int col = (nq * 2 + ci) * 16 + m;
        float gm = gamma[col], bt = beta[col];
#pragma unroll
        for (int r = 0; r < 4; ++r) {
          float hh = gelu((xc[ci * 4 + r] - mu[r]) * rv[r] * gm + bt);
          ah[(size_t)rowO[r] * AHS + 256 + col] = f2bf(hh);
        }
      }
    }
  } else {
    if (act) {
#pragma unroll
      for (int ci = 0; ci < 2; ++ci) {
        int col = (nq * 2 + ci) * 16 + m;
        float bias = bn[col];
#pragma unroll
        for (int r = 0; r < 4; ++r)
          x[(size_t)rowO[r] * DD + col] = xc[ci * 4 + r] + acc[ci][r] + bias;
      }
    }
  }
}

// ---------------------------------------------------------------------------
// 16-row top GEMM tile (rows 0..15 of batch b). Waves 0-7 = 8 col-tiles;
// waves 8-15 inactive. Called by ALL waves (runs alone, not concurrent).
__device__ __forceinline__ void ph_gemm16t(char* redc, int b,
                                           unsigned short* ah,
                                           const unsigned short* __restrict__ wfl,
                                           const float* __restrict__ bn,
                                           float* __restrict__ x, int hoff_in,
                                           const float* __restrict__ gamma,
                                           const float* __restrict__ beta,
                                           float* xc, int first_layer) {
  int ct = threadIdx.x >> 6, lane = threadIdx.x & 63;
  bool act = ct < 8;
  int m = lane & 15, q = lane >> 4;
  floatx4 acc = (floatx4){0.f, 0.f, 0.f, 0.f};
  int col = (ct & 7) * 16 + m;
  if (act) {
    const unsigned short* arow = ah + (size_t)(b * NN + m) * AHS + q * 8;
    const bf16x8* B = (const bf16x8*)wfl + lane;
#pragma unroll
    for (int kc = 0; kc < 8; ++kc) {
      int koff = (kc < 4) ? kc * 32 : hoff_in + (kc - 4) * 32;
      bf16x8 a0 = *(const bf16x8*)(arow + koff);
      bf16x8 bb = B[(kc * 8 + ct) * 64];
      acc = __builtin_amdgcn_mfma_f32_16x16x32_bf16(a0, bb, acc, 0, 0, 0);
    }
  }
  if (first_layer) {
    float s1[4] = {0.f, 0.f, 0.f, 0.f}, s2[4] = {0.f, 0.f, 0.f, 0.f};
    float bias = act ? bn[col] : 0.f;
    if (act) {
#pragma unroll
      for (int r = 0; r < 4; ++r) {
        float v = xc[r] + acc[r] + bias;
        xc[r] = v; s1[r] = v; s2[r] = v * v;
      }
#pragma unroll
      for (int r = 0; r < 4; ++r) {
        s1[r] += __shfl_xor(s1[r], 1); s2[r] += __shfl_xor(s2[r], 1);
        s1[r] += __shfl_xor(s1[r], 2); s2[r] += __shfl_xor(s2[r], 2);
        s1[r] += __shfl_xor(s1[r], 4); s2[r] += __shfl_xor(s2[r], 4);
        s1[r] += __shfl_xor(s1[r], 8); s2[r] += __shfl_xor(s2[r], 8);
      }
    }
    float* red = (float*)redc;
    __syncthreads();
    if (act && m == 0) {
#pragma unroll
      for (int r = 0; r < 4; ++r) {
        red[(q * 4 + r) * 8 + ct] = s1[r];
        red[128 + (q * 4 + r) * 8 + ct] = s2[r];
      }
    }
    __syncthreads();
    if (act) {
#pragma unroll
      for (int r = 0; r < 4; ++r) {
        float t1 = 0.f, t2 = 0.f;
#pragma unroll
        for (int j = 0; j < 8; ++j) {
          t1 += red[(q * 4 + r) * 8 + j];
          t2 += red[128 + (q * 4 + r) * 8 + j];
        }
        float mu = t1 * (1.0f / 128.0f);
        float var = t2 * (1.0f / 128.0f) - mu * mu;
        float rv = rsqrtf(var + 1e-5f);
        float hh = gelu((xc[r] - mu) * rv * gamma[col] + beta[col]);
        ah[(size_t)(b * NN + q * 4 + r) * AHS + 256 + col] = f2bf(hh);
      }
    }
  } else {
    if (act) {
      float bias = bn[col];
#pragma unroll
      for (int r = 0; r < 4; ++r)
        x[(size_t)(b * NN + q * 4 + r) * DD + col] = xc[r] + acc[r] + bias;
    }
  }
}

// ---------------------------------------------------------------------------
// Megakernel: 8 XCD-affine groups x 32 blocks (group = bid&7 = batch).
// gb 0-15: tree + t32 tile. gb 16-31: t0 tile of subtree gb-16.
// gb 16-23: CSR + eoff precompute. gb 24-27: weight repack. gb 28: top chain.
__global__ __launch_bounds__(NT, 1) void k_mega(
    const float* __restrict__ elements, const float* __restrict__ ln_gamma,
    const float* __restrict__ ln_beta, const float* __restrict__ w_nei,
    const float* __restrict__ b_nei, const float* __restrict__ w_root,
    const int* __restrict__ srcv, const int* __restrict__ dstv, int E,
    float* __restrict__ x, int* s0a, int* s1a, float* lvl4, float* sroot,
    unsigned short* wf, unsigned short* ah, unsigned short* eoff, int* bar) {
  __shared__ __align__(16) char smem[65536];
  int bid = blockIdx.x, tid = threadIdx.x;
  int b = bid & 7, gb = bid >> 3;    // XCD-affine: batch = bid % 8
  int Eb = E >> 3;
  unsigned short* wfg = wf + (size_t)b * 65536;
  float xcl[8], xci[8], xct[4];
  int wv = tid >> 6;

  // ---- P0 ----
  if (gb < 16) {
    ph_tree(smem, b, gb, elements, x, lvl4, ah, ln_gamma, ln_beta, sroot, xci, bar);
  } else if (gb < 24) {
    int base = b * Eb;
    for (int i = base + (gb - 16) * NT + tid; i < base + Eb; i += 8 * NT) {
      int dv = dstv[i];
      if (i == 0 || dstv[i - 1] != dv) s0a[dv] = i;
      if (i == base + Eb - 1 || dstv[i + 1] != dv) s1a[dv] = i + 1;
    }
    // precompute per-edge concatenated window ROW index for leaf-dst edges
    for (int i = base + (gb - 16) * NT + tid; i < base + Eb; i += 8 * NT) {
      int dl = dstv[i] - b * NN - 1024;
      unsigned short ov = 0xFFFFu;
      if (dl >= 0) {
        int jb2 = dl >> 5;
        int g = srcv[i] - b * NN;
        int lv = 31 - __clz(g);
        int acc2 = 0;
#pragma unroll
        for (int cd = 10; cd >= 1; --cd) {
          int lo_, wd_;
          win_cd(jb2, cd, lo_, wd_);
          if (cd == lv) {
            int idx = g - lo_;
            if ((unsigned)idx < (unsigned)wd_)
              ov = (unsigned short)(acc2 + idx);
          }
          acc2 += wd_;
        }
      }
      eoff[i] = ov;
    }
  } else if (gb < 28) {
    int gi = (gb - 24) * NT + tid;   // 0..4095 frag units
    int lane = gi & 63, ct = (gi >> 6) & 7, kc = gi >> 9;
    int n = ct * 16 + (lane & 15);
    int k = kc * 32 + (lane >> 4) * 8;
    int kk = k & 127;
#pragma unroll
    for (int l = 0; l < 2; ++l) {
      const float* w = (k < 128) ? (w_nei + (size_t)l * DD * DD)
                                 : (w_root + (size_t)l * DD * DD);
      unsigned short* o = wfg + (size_t)l * 32768 + (size_t)gi * 8;
#pragma unroll
      for (int j = 0; j < 8; ++j) o[j] = f2bf(w[(size_t)(kk + j) * DD + n]);
    }
  } else if (gb == 28) {
    // wait for all 16 lvl4 slices of this batch, then top-node x0 + h
    if (tid < 16) {
      while (!__hip_atomic_load(bar + 1536 + b * 64 + tid * 4, __ATOMIC_RELAXED,
                                __HIP_MEMORY_SCOPE_AGENT))
        __builtin_amdgcn_s_sleep(1);
      __threadfence();
    }
    __syncthreads();
    ph_top(smem, b, lvl4, ah, ln_gamma, ln_beta);  // xs in LDS, h0..15 -> ah
    {                                              // stash xct (waves 0-7)
      int ln = tid & 63, m_ = ln & 15, q_ = ln >> 4;
      if (wv < 8) {
        float (*xs)[DD] = (float(*)[DD])smem;
#pragma unroll
        for (int r = 0; r < 4; ++r) xct[r] = xs[q_ * 4 + r][wv * 16 + m_];
      }
    }
  }
  // zero msk(256 u32) + fb (+invdeg region; rewritten in P1 before use).
  // Address-disjoint from all last-phase LDS traffic above; ordered against
  // P1's edge-scatter by gbar0.
  if (tid < 289) *(unsigned*)(smem + MSK_OFF + 4 * tid) = 0u;
  gbarN(bar, 0);

  // ---- P1 (layer 0) ----
  if (gb == 28) {
    if (tid < 128) ph_topfin(b, sroot, ah, 128);
    __syncthreads();
    ph_gemm16t(smem + RED_OFF, b, ah, wfg, b_nei, x, 128,
               ln_gamma + DD, ln_beta + DD, xct, 1);
    __syncthreads();
  }
  ph_leafagg(smem, b, gb, srcv, dstv, s0a, s1a, eoff, ah, 128, 1);
  __syncthreads();
  if (wv < 8) {
    ph_gemm32(smem + RED_OFF, (const unsigned short*)(smem + AGGL_OFF),
              b * NN + 1024 + gb * 32, ah, wfg, b_nei, x, 128,
              ln_gamma + DD, ln_beta + DD, xcl, 1);
  } else if (gb < 16) {
    ph_gemm32s(smem + RED2_OFF, b, gb, 32, ah, wfg, b_nei, x, 128,
               ln_gamma + DD, ln_beta + DD, xci, 1, nullptr);
  } else {
    ph_gemm32s(smem + RED2_OFF, b, gb - 16, 0, ah, wfg, b_nei, x, 128,
               ln_gamma + DD, ln_beta + DD, xci, 1, x);
  }
  gbarN(bar, 1);

  // ---- P2 (layer 1): no group barrier; per-subtree aggsub flags order the
  // agg(ah+0) producer (block s) against its consumers (block 16+s, gb28) ----
  if (gb < 16) {
    ph_aggsub(smem, b, gb, ah, sroot);
    __syncthreads();
    if (tid == 0) {
      __threadfence();
      __hip_atomic_store(bar + 1024 + b * 64 + gb * 4, 1, __ATOMIC_RELAXED,
                         __HIP_MEMORY_SCOPE_AGENT);
    }
  }
  ph_leafagg(smem, b, gb, srcv, dstv, s0a, s1a, eoff, ah, 256, 0);
  if (gb >= 16 && tid == 0) {
    // acquire subtree gb-16's aggsub output before the t0-tile gemm reads agg
    while (!__hip_atomic_load(bar + 1024 + b * 64 + (gb - 16) * 4, __ATOMIC_RELAXED,
                              __HIP_MEMORY_SCOPE_AGENT))
      __builtin_amdgcn_s_sleep(1);
    __threadfence();
  }
  __syncthreads();
  if (wv < 8) {
    ph_gemm32(smem + RED_OFF, (const unsigned short*)(smem + AGGL_OFF),
              b * NN + 1024 + gb * 32, ah, wfg + 32768, b_nei + DD,
              x, 256, ln_gamma, ln_beta, xcl, 0);
  } else if (gb < 16) {
    ph_gemm32s(smem + RED2_OFF, b, gb, 32, ah, wfg + 32768, b_nei + DD, x, 256,
               ln_gamma, ln_beta, xci, 0, nullptr);
  } else {
    ph_gemm32s(smem + RED2_OFF, b, gb - 16, 0, ah, wfg + 32768, b_nei + DD, x, 256,
               ln_gamma, ln_beta, xci, 0, nullptr);
  }
  if (gb == 28) {
    if (tid < 16) {
      while (!__hip_atomic_load(bar + 1024 + b * 64 + tid * 4, __ATOMIC_RELAXED,
                                __HIP_MEMORY_SCOPE_AGENT))
        __builtin_amdgcn_s_sleep(1);
      __threadfence();
    }
    __syncthreads();
    if (tid < 128) ph_topfin(b, sroot, ah, 256);
    __syncthreads();
    ph_gemm16t(smem + RED_OFF, b, ah, wfg + 32768, b_nei + DD, x, 256,
               ln_gamma, ln_beta, xct, 0);
  }
}

// ---------------------------------------------------------------------------
extern "C" void kernel_launch(void* const* d_in, const int* in_sizes, int n_in,
                              void* d_out, int out_size, void* d_ws, size_t ws_size,
                              hipStream_t stream) {
  const float* elements = (const float*)d_in[0];
  const float* ln_gamma = (const float*)d_in[1];
  const float* ln_beta  = (const float*)d_in[2];
  const float* w_nei    = (const float*)d_in[3];
  const float* b_nei    = (const float*)d_in[4];
  const float* w_root   = (const float*)d_in[5];
  const int*   edge     = (const int*)d_in[6];
  int E = in_sizes[6] / 2;
  const int* srcv = edge;
  const int* dstv = edge + E;
  float* x = (float*)d_out;

  char* ws = (char*)d_ws;
  int*            bar   = (int*)ws;                         // 8 KB used
  int*            s0    = (int*)(ws + 65536);               // 64 KB
  int*            s1    = (int*)(ws + 131072);              // 64 KB
  float*          lvl4  = (float*)(ws + 196608);            // 64 KB
  float*          sroot = (float*)(ws + 262144);            // 64 KB
  unsigned short* wf    = (unsigned short*)(ws + 327680);   // 1 MB (8 copies)
  unsigned short* ah    = (unsigned short*)(ws + 327680 + 1048576);  // 12.6 MB
  unsigned short* eoff  = (unsigned short*)(ws + 327680 + 1048576 + 12582912); // 2E B

  hipMemsetAsync(bar, 0, 8192, stream);
  k_mega<<<dim3(NB), dim3(NT), 0, stream>>>(
      elements, ln_gamma, ln_beta, w_nei, b_nei, w_root,
      srcv, dstv, E, x, s0, s1, lvl4, sroot, wf, ah, eoff, bar);
}